// Round 3
// baseline (2430.359 us; speedup 1.0000x reference)
//
#include <hip/hip_runtime.h>

typedef unsigned short u16;
typedef unsigned int u32;

typedef __attribute__((ext_vector_type(8))) __bf16 bf16x8;
typedef __attribute__((ext_vector_type(4))) float f32x4;

__device__ __forceinline__ float bf2f(u16 u) {
    u32 t = ((u32)u) << 16;
    float f;
    __builtin_memcpy(&f, &t, 4);
    return f;
}
__device__ __forceinline__ u16 f2bf(float f) {
    u32 u;
    __builtin_memcpy(&u, &f, 4);
    u32 r = (u + 0x7fffu + ((u >> 16) & 1u)) >> 16;
    return (u16)r;
}
__device__ __forceinline__ float tanh_fast(float x) {
    float xc = fminf(fmaxf(x, -15.f), 15.f);
    float e = __expf(2.f * xc);
    return (e - 1.f) / (e + 1.f);
}

// Async global->LDS DMA, 16B per lane. LDS dest = wave-uniform base + lane*16.
// AS casts mirror LLVM's addrspacecast lowering (low 32 bits of a generic LDS
// pointer are the AS3 offset; generic global == AS1 bitwise).
__device__ __forceinline__ void gld16(const u16* g, u16* l) {
    __builtin_amdgcn_global_load_lds(
        (const __attribute__((address_space(1))) u32*)(uintptr_t)g,
        (__attribute__((address_space(3))) u32*)(u32)(uintptr_t)l,
        16, 0, 0);
}

// ---------------------------------------------------------------------------
// bf16 MFMA GEMM, tile TM x 128:  C[m,n] (+)= sum_t sum_k A_t[m,k]*W_t[n,k]
// A: [spatial][Bc][ldA] (k-contiguous). W: [T][N][ldW]. T==9 -> 3x3 conv via
// shift-GEMM, invalid shifts skipped (block-uniform since tile sits at one
// spatial position). TM=128: 4 waves 2x2 (64x64 each). TM=64: 4 waves 1x4
// (64m x 32n each). Staging via global_load_lds dwordx4 (m97 pattern).
// EPI 0: relu(acc*epiA[n]+epiB[n]); EPI 1: tanh(acc+epiB[n]).
// ---------------------------------------------------------------------------
template <int EPI, int TM>
__global__ __launch_bounds__(256, 2) void gemm_bt(
    const u16* __restrict__ A, const u16* __restrict__ W, u16* __restrict__ O,
    const float* __restrict__ epiA, const float* __restrict__ epiB,
    int Kin, int N, int T, int Himg, int Wimg,
    int ldA, int ldW, int ldO,
    long long Az, long long Wz, long long Oz, int epiZ,
    int Bc, int bshift)
{
    constexpr int NJ = (TM == 128) ? 4 : 2;
    __shared__ __align__(16) u16 lsA[TM * 32];
    __shared__ __align__(16) u16 lsW[128 * 32];

    const int tid = threadIdx.x;
    const int z = blockIdx.z;
    A += (long long)z * Az;
    W += (long long)z * Wz;
    O += (long long)z * Oz;
    epiB += (long long)z * epiZ;

    const int m0 = blockIdx.x * TM;
    const int n0 = blockIdx.y * 128;
    const int s = m0 >> bshift;          // spatial index (0 for MLP)
    const int b0 = m0 & (Bc - 1);        // batch offset
    const int hh0 = s / Wimg, ww0 = s % Wimg;

    const int wave = tid >> 6;
    const int lane = tid & 63;
    const int mbase = (TM == 128) ? (wave >> 1) * 64 : 0;
    const int nbase = (TM == 128) ? (wave & 1) * 64 : wave * 32;
    const int ln = lane & 15, qd = lane >> 4;

    const int srow = lane >> 2;          // 0..15 (staging row within 16-row slab)
    const int scol = (lane & 3) * 8;     // staging k offset in elems

    f32x4 acc[4][NJ];
#pragma unroll
    for (int i = 0; i < 4; ++i)
#pragma unroll
        for (int j = 0; j < NJ; ++j)
            acc[i][j] = (f32x4){0.f, 0.f, 0.f, 0.f};

    for (int t = 0; t < T; ++t) {
        int sp;
        if (T == 9) {
            int hh = hh0 + t / 3 - 1;
            int ww = ww0 + t % 3 - 1;
            if (hh < 0 || hh >= Himg || ww < 0 || ww >= Wimg) continue;  // block-uniform
            sp = hh * Wimg + ww;
        } else {
            sp = s;
        }
        const u16* At = A + (long long)(sp * Bc + b0) * ldA;
        const u16* Wt = W + ((long long)t * N + n0) * ldW;
        const int arow = (TM == 128) ? (wave * 32 + srow) : (wave * 16 + srow);
        const u16* gA0 = At + (long long)arow * ldA + scol;
        const u16* gA1 = gA0 + 16 * ldA;                  // TM==128 only
        const u16* gW0 = Wt + (long long)(wave * 32 + srow) * ldW + scol;
        const u16* gW1 = gW0 + 16 * ldW;
        u16* lA0 = lsA + ((TM == 128) ? wave * 1024 : wave * 512);
        u16* lA1 = lA0 + 512;
        u16* lW0 = lsW + wave * 1024;
        u16* lW1 = lW0 + 512;

        for (int k0 = 0; k0 < Kin; k0 += 32) {
            __syncthreads();                 // prev iter's LDS fully consumed
            gld16(gA0 + k0, lA0);
            if (TM == 128) gld16(gA1 + k0, lA1);
            gld16(gW0 + k0, lW0);
            gld16(gW1 + k0, lW1);
            __syncthreads();                 // drains vmcnt -> LDS ready

            bf16x8 af[4], bfr[NJ];
#pragma unroll
            for (int f = 0; f < 4; ++f)
                af[f] = *(const bf16x8*)&lsA[(mbase + f * 16 + ln) * 32 + qd * 8];
#pragma unroll
            for (int f = 0; f < NJ; ++f)
                bfr[f] = *(const bf16x8*)&lsW[(nbase + f * 16 + ln) * 32 + qd * 8];
#pragma unroll
            for (int i = 0; i < 4; ++i)
#pragma unroll
                for (int j = 0; j < NJ; ++j)
                    acc[i][j] = __builtin_amdgcn_mfma_f32_16x16x32_bf16(
                        af[i], bfr[j], acc[i][j], 0, 0, 0);
        }
    }

#pragma unroll
    for (int j = 0; j < NJ; ++j) {
        const int n = n0 + nbase + j * 16 + ln;
        const float sh = epiB[n];
        float sc = 1.f;
        if (EPI == 0) sc = epiA[n];
#pragma unroll
        for (int i = 0; i < 4; ++i) {
            const int mrow = mbase + i * 16 + qd * 4;
#pragma unroll
            for (int rr = 0; rr < 4; ++rr) {
                float v = acc[i][j][rr];
                if (EPI == 0) v = fmaxf(v * sc + sh, 0.f);
                else          v = tanh_fast(v + sh);
                O[(long long)(m0 + mrow + rr) * ldO + n] = f2bf(v);
            }
        }
    }
}

// ---------------------------------------------------------------------------
// x chunk [Bc,3,20,20] fp32 -> xt [400][Bc][3] bf16
// ---------------------------------------------------------------------------
__global__ __launch_bounds__(256) void transpose_x(
    const float* __restrict__ x, u16* __restrict__ xt, int Bc, int bshift)
{
    const int t = blockIdx.x * 256 + threadIdx.x;
    if (t >= 400 * Bc) return;
    const int s = t >> bshift;
    const int b = t & (Bc - 1);
    const float v0 = x[((long long)b * 3 + 0) * 400 + s];
    const float v1 = x[((long long)b * 3 + 1) * 400 + s];
    const float v2 = x[((long long)b * 3 + 2) * 400 + s];
    u16* o = xt + ((long long)s * Bc + b) * 3;
    o[0] = f2bf(v0); o[1] = f2bf(v1); o[2] = f2bf(v2);
}

// ---------------------------------------------------------------------------
// Fused conv1+BN+ReLU+maxpool(3,2,1): xt[400][Bc][3] -> p1[100][Bc][64]
// 4 channels per thread; (so, chgroup) block-uniform -> weights are scalar
// loads; px patch (75 fp32) in registers. __launch_bounds__(256,2): allow up
// to 256 VGPR (round-2 version was capped at 64 and spilled 67 MB/dispatch).
// ---------------------------------------------------------------------------
__global__ __launch_bounds__(256, 2) void conv1_pool1(
    const u16* __restrict__ xt, const float* __restrict__ W1,
    const float* __restrict__ bnA, const float* __restrict__ bnB,
    u16* __restrict__ p1, int Bc)
{
    const int b = blockIdx.x * 256 + threadIdx.x;
    const int so = blockIdx.y;                 // pooled spatial 0..99
    const int cg = blockIdx.z;                 // channel group of 4, 0..15
    const int ho = so / 10, wo = so % 10;

    float px[5][5][3];
#pragma unroll
    for (int rI = 0; rI < 5; ++rI) {
        const int hr = 2 * ho - 2 + rI;
#pragma unroll
        for (int c = 0; c < 5; ++c) {
            const int wc = 2 * wo - 2 + c;
            if (hr >= 0 && hr < 20 && wc >= 0 && wc < 20) {
                const u16* q = xt + ((long long)(hr * 20 + wc) * Bc + b) * 3;
                px[rI][c][0] = bf2f(q[0]);
                px[rI][c][1] = bf2f(q[1]);
                px[rI][c][2] = bf2f(q[2]);
            } else {
                px[rI][c][0] = 0.f; px[rI][c][1] = 0.f; px[rI][c][2] = 0.f;
            }
        }
    }

    u32 pk[2];
#pragma unroll
    for (int uu = 0; uu < 4; ++uu) {
        const int co = cg * 4 + uu;
        const float sA = bnA[co], sB = bnB[co];
        float best = 0.f;                      // relu floor (relu commutes with max)
#pragma unroll
        for (int ph = 0; ph < 3; ++ph) {
            const int hwin = 2 * ho - 1 + ph;
            if (hwin < 0 || hwin >= 20) continue;   // scalar branch (so uniform)
#pragma unroll
            for (int pw = 0; pw < 3; ++pw) {
                const int wwin = 2 * wo - 1 + pw;
                if (wwin < 0 || wwin >= 20) continue;
                float sacc = 0.f;
#pragma unroll
                for (int q = 0; q < 27; ++q) {
                    const int ci = q / 9, kh = (q % 9) / 3, kw = q % 3;
                    sacc += W1[co * 27 + q] * px[ph + kh][pw + kw][ci];
                }
                best = fmaxf(best, sacc * sA + sB);  // bnA>0: affine commutes with max
            }
        }
        const u16 hv = f2bf(best);
        if (uu & 1) pk[uu >> 1] |= ((u32)hv) << 16;
        else        pk[uu >> 1] = (u32)hv;
    }
    uint2 st; st.x = pk[0]; st.y = pk[1];
    *(uint2*)(p1 + ((long long)so * Bc + b) * 64 + cg * 4) = st;
}

// ---------------------------------------------------------------------------
// pool2: a2[100][Bc][128] -> p2[25][Bc][128]  (values already relu'd, >= 0)
// ---------------------------------------------------------------------------
__global__ __launch_bounds__(256) void pool2_k(
    const u16* __restrict__ a2, u16* __restrict__ p2, int Bc)
{
    const int t = blockIdx.x * 256 + threadIdx.x;  // Bc*16 threads
    const int cc = t & 15;
    const int b = t >> 4;
    if (b >= Bc) return;
    const int so = blockIdx.y;
    const int ho = so / 5, wo = so % 5;
    float best[8];
#pragma unroll
    for (int e = 0; e < 8; ++e) best[e] = 0.f;
    for (int ph = 0; ph < 3; ++ph) {
        const int hh = 2 * ho - 1 + ph;
        if (hh < 0 || hh >= 10) continue;
        for (int pw = 0; pw < 3; ++pw) {
            const int ww = 2 * wo - 1 + pw;
            if (ww < 0 || ww >= 10) continue;
            const uint4 u = *(const uint4*)(a2 + ((long long)(hh * 10 + ww) * Bc + b) * 128 + cc * 8);
            const u32 uw[4] = {u.x, u.y, u.z, u.w};
#pragma unroll
            for (int e = 0; e < 4; ++e) {
                best[2 * e]     = fmaxf(best[2 * e],     bf2f((u16)(uw[e] & 0xffff)));
                best[2 * e + 1] = fmaxf(best[2 * e + 1], bf2f((u16)(uw[e] >> 16)));
            }
        }
    }
    u32 pk[4];
#pragma unroll
    for (int e = 0; e < 4; ++e)
        pk[e] = (u32)f2bf(best[2 * e]) | (((u32)f2bf(best[2 * e + 1])) << 16);
    uint4 st;
    st.x = pk[0]; st.y = pk[1]; st.z = pk[2]; st.w = pk[3];
    *(uint4*)(p2 + ((long long)so * Bc + b) * 128 + cc * 8) = st;
}

// ---------------------------------------------------------------------------
// Head: logits(600->10)+softmax from h[n][Bc][640] bf16. n = blockIdx.y so Wb
// accesses are provably wave-uniform -> scalar loads.
// STAGE 1 -> preds bf16 [25][Bc][10]; STAGE 2 -> d_out fp32.
// ---------------------------------------------------------------------------
template <int STAGE>
__global__ __launch_bounds__(256) void logits_softmax(
    const u16* __restrict__ h, const float* __restrict__ Wb, const float* __restrict__ bb,
    u16* __restrict__ preds, float* __restrict__ dout, int Bc, int gbase)
{
    const int b = blockIdx.x * 256 + threadIdx.x;
    const int n = blockIdx.y;
    const u16* hr = h + ((long long)n * Bc + b) * 640;
    const float* Wn = Wb + n * 6000;
    float acc[10];
#pragma unroll
    for (int j = 0; j < 10; ++j) acc[j] = bb[n * 10 + j];
    for (int c0 = 0; c0 < 600; c0 += 4) {
        const uint2 u = *(const uint2*)(hr + c0);
        float hv[4];
        hv[0] = bf2f((u16)(u.x & 0xffff));
        hv[1] = bf2f((u16)(u.x >> 16));
        hv[2] = bf2f((u16)(u.y & 0xffff));
        hv[3] = bf2f((u16)(u.y >> 16));
#pragma unroll
        for (int e = 0; e < 4; ++e)
#pragma unroll
            for (int j = 0; j < 10; ++j)
                acc[j] += hv[e] * Wn[(c0 + e) * 10 + j];
    }
    float mx = acc[0];
#pragma unroll
    for (int j = 1; j < 10; ++j) mx = fmaxf(mx, acc[j]);
    float p[10], ssum = 0.f;
#pragma unroll
    for (int j = 0; j < 10; ++j) { p[j] = __expf(acc[j] - mx); ssum += p[j]; }
    const float inv = 1.f / ssum;
    if (STAGE == 1) {
        u16* o = preds + ((long long)n * Bc + b) * 10;
#pragma unroll
        for (int j = 0; j < 10; ++j) o[j] = f2bf(p[j] * inv);
    } else {
        float* o = dout + 81920 + ((long long)n * 8192 + gbase + b) * 10;
#pragma unroll
        for (int j = 0; j < 10; ++j) o[j] = p[j] * inv;
    }
}

// ---------------------------------------------------------------------------
// Stage-2 input assembly: A2[n][b][0:80]=masked neighbor preds, [80:336]=feats,
// [336:352]=0.
// ---------------------------------------------------------------------------
__device__ __forceinline__ void neighbors5x5(int i, int* nb) {
    const int w = 5, size = 25;
    int cnt = 0;
    if (i - w >= 0) nb[cnt++] = i - w;
    if (i % w != 0) nb[cnt++] = i - 1;
    if ((i + 1) % w != 0) nb[cnt++] = i + 1;
    if (i + w < size) nb[cnt++] = i + w;
    if (i - w - 1 >= 0 && i % w != 0) nb[cnt++] = i - w - 1;
    if (i - w + 1 >= 0 && (i + 1) % w != 0) nb[cnt++] = i - w + 1;
    if (i + w - 1 < size && i % w != 0) nb[cnt++] = i + w - 1;
    if (i + w + 1 < size && (i + 1) % w != 0) nb[cnt++] = i + w + 1;
    for (; cnt < 8; ++cnt) nb[cnt] = -1;
}

__global__ __launch_bounds__(256) void gather_nb(
    const u16* __restrict__ preds, const u16* __restrict__ feats, u16* __restrict__ A2,
    int Bc, int bshift)
{
    const int g = blockIdx.x * 256 + threadIdx.x;  // n*Bc+b
    if (g >= 25 * Bc) return;
    const int n = g >> bshift;
    const int b = g & (Bc - 1);
    int nb[8];
    neighbors5x5(n, nb);
    u16* dst = A2 + (long long)g * 352;
#pragma unroll
    for (int j = 0; j < 8; ++j) {
        u32* d32 = (u32*)(dst + j * 10);
        if (nb[j] >= 0) {
            const u32* s32 = (const u32*)(preds + ((long long)nb[j] * Bc + b) * 10);
#pragma unroll
            for (int q = 0; q < 5; ++q) d32[q] = s32[q];
        } else {
#pragma unroll
            for (int q = 0; q < 5; ++q) d32[q] = 0u;
        }
    }
    const uint4* fs = (const uint4*)(feats + (long long)g * 256);
    uint4* fd = (uint4*)(dst + 80);
#pragma unroll
    for (int q = 0; q < 32; ++q) fd[q] = fs[q];
    uint4 z;
    z.x = 0u; z.y = 0u; z.z = 0u; z.w = 0u;
    *(uint4*)(dst + 336) = z;
    *(uint4*)(dst + 344) = z;
}

// ---------------------------------------------------------------------------
// mean over nodes: d_out[0:81920] = mean_n second[n]  (full batch, run once)
// ---------------------------------------------------------------------------
__global__ __launch_bounds__(256) void mean_k(float* __restrict__ dout)
{
    const int t = blockIdx.x * 256 + threadIdx.x;
    float s = 0.f;
#pragma unroll
    for (int n = 0; n < 25; ++n) s += dout[81920 + n * 81920 + t];
    dout[t] = s * 0.04f;
}

// ---------------------------------------------------------------------------
// Weight/param prep (once per launch)
// ---------------------------------------------------------------------------
__global__ void prep_bn_all(
    const float* b1, const float* g1, const float* be1, const float* m1, const float* v1,
    const float* b2, const float* g2, const float* be2, const float* m2, const float* v2,
    const float* b3, const float* g3, const float* be3, const float* m3, const float* v3,
    const float* b4, const float* g4, const float* be4, const float* m4, const float* v4,
    float* bnA, float* bnB)
{
    const int t = blockIdx.x * 256 + threadIdx.x;
    if (t >= 704) return;
    const float *bp, *gp, *bep, *mp, *vp;
    int idx;
    if (t < 64)       { bp=b1; gp=g1; bep=be1; mp=m1; vp=v1; idx=t; }
    else if (t < 192) { bp=b2; gp=g2; bep=be2; mp=m2; vp=v2; idx=t-64; }
    else if (t < 448) { bp=b3; gp=g3; bep=be3; mp=m3; vp=v3; idx=t-192; }
    else              { bp=b4; gp=g4; bep=be4; mp=m4; vp=v4; idx=t-448; }
    const float A = gp[idx] * rsqrtf(vp[idx] + 1e-5f);
    bnA[t] = A;
    bnB[t] = (bp[idx] - mp[idx]) * A + bep[idx];
}

__global__ void prep_convw(const float* __restrict__ W, u16* __restrict__ Wt, int Co, int Ci)
{
    const int t = blockIdx.x * 256 + threadIdx.x;
    const int tot = 9 * Co * Ci;
    if (t >= tot) return;
    const int sh = t / (Co * Ci);
    const int rem = t % (Co * Ci);
    const int co = rem / Ci, ci = rem % Ci;
    Wt[t] = f2bf(W[(long long)(co * Ci + ci) * 9 + sh]);
}

__global__ void prep_wat(const float* __restrict__ Wa, u16* __restrict__ Wat)
{
    const int t = blockIdx.x * 256 + threadIdx.x;
    if (t >= 25 * 640 * 352) return;
    const int n = t / (640 * 352);
    const int rem = t % (640 * 352);
    const int hcol = rem / 352;
    const int k = rem % 352;
    float v = 0.f;
    if (hcol < 600 && k < 336) v = Wa[((long long)n * 336 + k) * 600 + hcol];
    Wat[t] = f2bf(v);
}

__global__ void prep_ba(const float* __restrict__ ba, float* __restrict__ bap)
{
    const int t = blockIdx.x * 256 + threadIdx.x;
    if (t >= 25 * 640) return;
    const int n = t / 640, hcol = t % 640;
    bap[t] = (hcol < 600) ? ba[n * 600 + hcol] : 0.f;
}

// ---------------------------------------------------------------------------
extern "C" void kernel_launch(void* const* d_in, const int* in_sizes, int n_in,
                              void* d_out, int out_size, void* d_ws, size_t ws_size,
                              hipStream_t stream)
{
    (void)in_sizes; (void)n_in; (void)out_size;

    const float* x  = (const float*)d_in[0];
    const float* W1 = (const float*)d_in[1];
    const float* b1 = (const float*)d_in[2];
    const float* g1 = (const float*)d_in[3];
    const float* be1= (const float*)d_in[4];
    const float* m1 = (const float*)d_in[5];
    const float* v1 = (const float*)d_in[6];
    const float* W2 = (const float*)d_in[7];
    const float* b2 = (const float*)d_in[8];
    const float* g2 = (const float*)d_in[9];
    const float* be2= (const float*)d_in[10];
    const float* m2 = (const float*)d_in[11];
    const float* v2 = (const float*)d_in[12];
    const float* W3 = (const float*)d_in[13];
    const float* b3 = (const float*)d_in[14];
    const float* g3 = (const float*)d_in[15];
    const float* be3= (const float*)d_in[16];
    const float* m3 = (const float*)d_in[17];
    const float* v3 = (const float*)d_in[18];
    const float* W4 = (const float*)d_in[19];
    const float* b4 = (const float*)d_in[20];
    const float* g4 = (const float*)d_in[21];
    const float* be4= (const float*)d_in[22];
    const float* m4 = (const float*)d_in[23];
    const float* v4 = (const float*)d_in[24];
    const float* Wa = (const float*)d_in[25];
    const float* ba = (const float*)d_in[26];
    const float* Wb = (const float*)d_in[27];
    const float* bb = (const float*)d_in[28];
    float* dout = (float*)d_out;

    // ---- choose Bc: overlay peak = 49600 bytes per batch element ----
    auto al = [](long long v) { return (v + 255LL) & ~255LL; };
    const long long fixedB = al(147456) + al(589824) + al(1179648) +
                             al(11264000) + al(64000) + al(2816) + al(2816);
    int Bc = 256;
    for (int cand = 2048; cand >= 256; cand >>= 1) {
        long long need = fixedB + al(49600LL * cand);
        if (need <= (long long)ws_size) { Bc = cand; break; }
    }
    const int bshift = __builtin_ctz((unsigned)Bc);
    const int C = 8192 / Bc;

    // ---- workspace: fixed region + one overlaid chunk region ----
    char* wsp = (char*)d_ws;
    long long off = 0;
    auto alloc = [&](long long bytes) { long long o = off; off += al(bytes); return o; };
    u16* Wt2  = (u16*)(wsp + alloc(147456));
    u16* Wt3  = (u16*)(wsp + alloc(589824));
    u16* Wt4  = (u16*)(wsp + alloc(1179648));
    u16* Wat  = (u16*)(wsp + alloc(11264000));
    float* bap = (float*)(wsp + alloc(64000));
    float* bnA = (float*)(wsp + alloc(2816));
    float* bnB = (float*)(wsp + alloc(2816));
    char* ch = wsp + alloc(49600LL * Bc);
    // overlay offsets (bytes per batch elem), lifetimes verified:
    u16* xt   = (u16*)(ch + 0LL     * Bc);   // [0,2400)    t1
    u16* p1   = (u16*)(ch + 2400LL  * Bc);   // [2400,15200) t1-t2
    u16* a2   = (u16*)(ch + 15200LL * Bc);   // [15200,40800) t2-t3
    u16* p2   = (u16*)(ch + 0LL     * Bc);   // [0,6400)    t3-t4
    u16* a3   = (u16*)(ch + 6400LL  * Bc);   // [6400,19200) t4-t5
    u16* a4   = (u16*)(ch + 32000LL * Bc);   // [32000,44800) t5-t8
    u16* h1   = (u16*)(ch + 0LL     * Bc);   // [0,32000)   t6-t7
    u16* preds= (u16*)(ch + 44800LL * Bc);   // [44800,45300) t7-t8
    u16* A2   = (u16*)(ch + 0LL     * Bc);   // [0,17600)   t8-t9
    u16* h2   = (u16*)(ch + 17600LL * Bc);   // [17600,49600) t9-t10

    // ---- prep (once) ----
    prep_bn_all<<<dim3(3), 256, 0, stream>>>(b1,g1,be1,m1,v1, b2,g2,be2,m2,v2,
                                             b3,g3,be3,m3,v3, b4,g4,be4,m4,v4, bnA, bnB);
    prep_convw<<<dim3(288),  256, 0, stream>>>(W2, Wt2, 128, 64);
    prep_convw<<<dim3(1152), 256, 0, stream>>>(W3, Wt3, 256, 128);
    prep_convw<<<dim3(2304), 256, 0, stream>>>(W4, Wt4, 256, 256);
    prep_wat<<<dim3(22000), 256, 0, stream>>>(Wa, Wat);
    prep_ba<<<dim3(63), 256, 0, stream>>>(ba, bap);

    // ---- batch chunks ----
    for (int c = 0; c < C; ++c) {
        const float* xc = x + (long long)c * Bc * 1200;

        transpose_x<<<dim3(400 * Bc / 256), 256, 0, stream>>>(xc, xt, Bc, bshift);
        conv1_pool1<<<dim3(Bc / 256, 100, 16), 256, 0, stream>>>(xt, W1, bnA, bnB, p1, Bc);
        gemm_bt<0,128><<<dim3(100 * Bc / 128, 1), 256, 0, stream>>>(p1, Wt2, a2, bnA + 64, bnB + 64,
            64, 128, 9, 10, 10, 64, 64, 128, 0LL, 0LL, 0LL, 0, Bc, bshift);
        pool2_k<<<dim3(Bc / 16, 25), 256, 0, stream>>>(a2, p2, Bc);
        gemm_bt<0,64><<<dim3(25 * Bc / 64, 2), 256, 0, stream>>>(p2, Wt3, a3, bnA + 192, bnB + 192,
            128, 256, 9, 5, 5, 128, 128, 256, 0LL, 0LL, 0LL, 0, Bc, bshift);
        gemm_bt<0,64><<<dim3(25 * Bc / 64, 2), 256, 0, stream>>>(a3, Wt4, a4, bnA + 448, bnB + 448,
            256, 256, 9, 5, 5, 256, 256, 256, 0LL, 0LL, 0LL, 0, Bc, bshift);

        // stage 1 MLP: zeros||feats -> only k-rows [80:336) of Wa matter
        gemm_bt<1,128><<<dim3(Bc / 128, 5, 25), 256, 0, stream>>>(a4, Wat + 80, h1, nullptr, bap,
            256, 640, 1, 1, 1, 256, 352, 640,
            (long long)Bc * 256, 640LL * 352, (long long)Bc * 640, 640, Bc, bshift);
        logits_softmax<1><<<dim3(Bc / 256, 25), 256, 0, stream>>>(
            h1, Wb, bb, preds, nullptr, Bc, 0);

        // stage 2
        gather_nb<<<dim3(25 * Bc / 256, 1), 256, 0, stream>>>(preds, a4, A2, Bc, bshift);
        gemm_bt<1,128><<<dim3(Bc / 128, 5, 25), 256, 0, stream>>>(A2, Wat, h2, nullptr, bap,
            352, 640, 1, 1, 1, 352, 352, 640,
            (long long)Bc * 352, 640LL * 352, (long long)Bc * 640, 640, Bc, bshift);
        logits_softmax<2><<<dim3(Bc / 256, 25), 256, 0, stream>>>(
            h2, Wb, bb, nullptr, dout, Bc, c * Bc);
    }

    mean_k<<<dim3(320), 256, 0, stream>>>(dout);
}

// Round 4
// 2064.532 us; speedup vs baseline: 1.1772x; 1.1772x over previous
//
#include <hip/hip_runtime.h>

typedef unsigned short u16;
typedef unsigned int u32;

typedef __attribute__((ext_vector_type(8))) __bf16 bf16x8;
typedef __attribute__((ext_vector_type(4))) float f32x4;

__device__ __forceinline__ float bf2f(u16 u) {
    u32 t = ((u32)u) << 16;
    float f;
    __builtin_memcpy(&f, &t, 4);
    return f;
}
__device__ __forceinline__ u16 f2bf(float f) {
    u32 u;
    __builtin_memcpy(&u, &f, 4);
    u32 r = (u + 0x7fffu + ((u >> 16) & 1u)) >> 16;
    return (u16)r;
}
__device__ __forceinline__ float tanh_fast(float x) {
    float xc = fminf(fmaxf(x, -15.f), 15.f);
    float e = __expf(2.f * xc);
    return (e - 1.f) / (e + 1.f);
}

// Async global->LDS DMA, 16B per lane. LDS dest = wave-uniform base + lane*16.
__device__ __forceinline__ void gld16(const u16* g, u16* l) {
    __builtin_amdgcn_global_load_lds(
        (const __attribute__((address_space(1))) u32*)(uintptr_t)g,
        (__attribute__((address_space(3))) u32*)(u32)(uintptr_t)l,
        16, 0, 0);
}

// ---------------------------------------------------------------------------
// bf16 MFMA GEMM, tile 128 x NT:  C[m,n] (+)= sum_t sum_k A_t[m,k]*W_t[n,k]
// A: [spatial][Bc][ldA] (k-contiguous). W: [T][N][ldW]. T==9 -> 3x3 conv via
// shift-GEMM, invalid shifts skipped (block-uniform: tile sits at one spatial
// position). 4 waves: 2x2 partition; NT=128 -> 64x64/wave, NT=64 -> 64x32/wave.
// Staging via global_load_lds dwordx4. launch_bounds (256,3): ~170 VGPR cap ->
// 3 blocks/CU (m97 operating point).
// EPI 0: relu(acc*epiA[n]+epiB[n]); EPI 1: tanh(acc+epiB[n]).
// ---------------------------------------------------------------------------
template <int EPI, int NT>
__global__ __launch_bounds__(256, 3) void gemm_bt(
    const u16* __restrict__ A, const u16* __restrict__ W, u16* __restrict__ O,
    const float* __restrict__ epiA, const float* __restrict__ epiB,
    int Kin, int N, int T, int Himg, int Wimg,
    int ldA, int ldW, int ldO,
    long long Az, long long Wz, long long Oz, int epiZ,
    int Bc, int bshift)
{
    constexpr int NJ = NT / 32;          // 4 (NT=128) or 2 (NT=64)
    __shared__ __align__(16) u16 lsA[128 * 32];
    __shared__ __align__(16) u16 lsW[NT * 32];

    const int tid = threadIdx.x;
    const int z = blockIdx.z;
    A += (long long)z * Az;
    W += (long long)z * Wz;
    O += (long long)z * Oz;
    epiB += (long long)z * epiZ;

    const int m0 = blockIdx.x * 128;
    const int n0 = blockIdx.y * NT;
    const int s = m0 >> bshift;          // spatial index (chunk row for flat-M)
    const int b0 = m0 & (Bc - 1);        // batch offset
    const int hh0 = s / Wimg, ww0 = s % Wimg;

    const int wave = tid >> 6;
    const int lane = tid & 63;
    const int mbase = (wave >> 1) * 64;
    const int nbase = (wave & 1) * (NT / 2);
    const int ln = lane & 15, qd = lane >> 4;

    const int srow = lane >> 2;          // 0..15 (staging row within 16-row slab)
    const int scol = (lane & 3) * 8;     // staging k offset in elems

    f32x4 acc[4][NJ];
#pragma unroll
    for (int i = 0; i < 4; ++i)
#pragma unroll
        for (int j = 0; j < NJ; ++j)
            acc[i][j] = (f32x4){0.f, 0.f, 0.f, 0.f};

    for (int t = 0; t < T; ++t) {
        int sp;
        if (T == 9) {
            int hh = hh0 + t / 3 - 1;
            int ww = ww0 + t % 3 - 1;
            if (hh < 0 || hh >= Himg || ww < 0 || ww >= Wimg) continue;  // block-uniform
            sp = hh * Wimg + ww;
        } else {
            sp = s;
        }
        const u16* At = A + (long long)(sp * Bc + b0) * ldA;
        const u16* Wt = W + ((long long)t * N + n0) * ldW;
        const u16* gA0 = At + (long long)(wave * 32 + srow) * ldA + scol;
        const u16* gA1 = gA0 + 16 * ldA;
        u16* lA0 = lsA + wave * 1024;
        u16* lA1 = lA0 + 512;
        const u16* gW0;
        u16* lW0;
        if (NT == 128) {
            gW0 = Wt + (long long)(wave * 32 + srow) * ldW + scol;
            lW0 = lsW + wave * 1024;
        } else {
            gW0 = Wt + (long long)(wave * 16 + srow) * ldW + scol;
            lW0 = lsW + wave * 512;
        }
        const u16* gW1 = gW0 + 16 * ldW;   // NT==128 only
        u16* lW1 = lW0 + 512;

        for (int k0 = 0; k0 < Kin; k0 += 32) {
            __syncthreads();                 // prev iter's LDS fully consumed
            gld16(gA0 + k0, lA0);
            gld16(gA1 + k0, lA1);
            gld16(gW0 + k0, lW0);
            if (NT == 128) gld16(gW1 + k0, lW1);
            __syncthreads();                 // drains vmcnt -> LDS ready

            bf16x8 af[4], bfr[NJ];
#pragma unroll
            for (int f = 0; f < 4; ++f)
                af[f] = *(const bf16x8*)&lsA[(mbase + f * 16 + ln) * 32 + qd * 8];
#pragma unroll
            for (int f = 0; f < NJ; ++f)
                bfr[f] = *(const bf16x8*)&lsW[(nbase + f * 16 + ln) * 32 + qd * 8];
#pragma unroll
            for (int i = 0; i < 4; ++i)
#pragma unroll
                for (int j = 0; j < NJ; ++j)
                    acc[i][j] = __builtin_amdgcn_mfma_f32_16x16x32_bf16(
                        af[i], bfr[j], acc[i][j], 0, 0, 0);
        }
    }

#pragma unroll
    for (int j = 0; j < NJ; ++j) {
        const int n = n0 + nbase + j * 16 + ln;
        const float sh = epiB[n];
        float sc = 1.f;
        if (EPI == 0) sc = epiA[n];
#pragma unroll
        for (int i = 0; i < 4; ++i) {
            const int mrow = mbase + i * 16 + qd * 4;
#pragma unroll
            for (int rr = 0; rr < 4; ++rr) {
                float v = acc[i][j][rr];
                if (EPI == 0) v = fmaxf(v * sc + sh, 0.f);
                else          v = tanh_fast(v + sh);
                O[(long long)(m0 + mrow + rr) * ldO + n] = f2bf(v);
            }
        }
    }
}

// ---------------------------------------------------------------------------
// x chunk [Bc,3,20,20] fp32 -> xt [400][Bc][4] bf16 (ch padded to 4, pad=0)
// ---------------------------------------------------------------------------
__global__ __launch_bounds__(256) void transpose_x(
    const float* __restrict__ x, u16* __restrict__ xt, int Bc, int bshift)
{
    const int t = blockIdx.x * 256 + threadIdx.x;
    if (t >= 400 * Bc) return;
    const int s = t >> bshift;
    const int b = t & (Bc - 1);
    const u32 c0 = f2bf(x[((long long)b * 3 + 0) * 400 + s]);
    const u32 c1 = f2bf(x[((long long)b * 3 + 1) * 400 + s]);
    const u32 c2 = f2bf(x[((long long)b * 3 + 2) * 400 + s]);
    uint2 st;
    st.x = c0 | (c1 << 16);
    st.y = c2;                              // high 16 = 0 pad
    *(uint2*)(xt + ((long long)s * Bc + b) * 4) = st;
}

// ---------------------------------------------------------------------------
// im2col for conv1: xt[400][Bc][4] -> xcol[400][Bc][32] (k = tap*3+ci, pad 0).
// Pure scalars (no private arrays -> no scratch). s is block-uniform.
// ---------------------------------------------------------------------------
__global__ __launch_bounds__(256) void im2col1(
    const u16* __restrict__ xt, u16* __restrict__ xcol, int Bc, int bshift)
{
    const int t = blockIdx.x * 256 + threadIdx.x;
    if (t >= 400 * Bc) return;
    const int s = t >> bshift;
    const int b = t & (Bc - 1);
    const int hh = s / 20, ww = s % 20;

    u32 p0, q0, p1, q1, p2, q2, p3, q3, p4, q4, p5, q5, p6, q6, p7, q7, p8, q8;
#define LOADTAP(T, P, Q)                                                      \
    {                                                                         \
        const int ih = hh + (T) / 3 - 1, iw = ww + (T) % 3 - 1;               \
        P = 0u; Q = 0u;                                                       \
        if (ih >= 0 && ih < 20 && iw >= 0 && iw < 20) {                       \
            const uint2 v = *(const uint2*)(xt +                              \
                ((long long)(ih * 20 + iw) * Bc + b) * 4);                    \
            P = v.x; Q = v.y;                                                 \
        }                                                                     \
    }
    LOADTAP(0, p0, q0) LOADTAP(1, p1, q1) LOADTAP(2, p2, q2)
    LOADTAP(3, p3, q3) LOADTAP(4, p4, q4) LOADTAP(5, p5, q5)
    LOADTAP(6, p6, q6) LOADTAP(7, p7, q7) LOADTAP(8, p8, q8)
#undef LOADTAP

    u16* o = xcol + (long long)t * 32;
    uint4 w;
    // taps (0,1) -> words 0..2 ; (2,3) -> 3..5 ; (4,5) -> 6..8 ; (6,7) -> 9..11
    w.x = p0;                w.y = q0 | (p1 << 16);
    w.z = (p1 >> 16) | (q1 << 16);
    w.w = p2;
    *(uint4*)(o + 0) = w;
    w.x = q2 | (p3 << 16);   w.y = (p3 >> 16) | (q3 << 16);
    w.z = p4;                w.w = q4 | (p5 << 16);
    *(uint4*)(o + 8) = w;
    w.x = (p5 >> 16) | (q5 << 16);
    w.y = p6;                w.z = q6 | (p7 << 16);
    w.w = (p7 >> 16) | (q7 << 16);
    *(uint4*)(o + 16) = w;
    w.x = p8;                w.y = q8;   // k=24..26 (+pad)
    w.z = 0u;                w.w = 0u;
    *(uint4*)(o + 24) = w;
}

// ---------------------------------------------------------------------------
// maxpool 3x3 s2 p1, square maps: src[Hi*Hi][Bc][CH] -> dst[Ho*Ho][Bc][CH].
// Values already relu'd (>= 0) so pool floor = 0.
// ---------------------------------------------------------------------------
template <int CH>
__global__ __launch_bounds__(256) void pool_k(
    const u16* __restrict__ src, u16* __restrict__ dst, int Bc, int Hi, int Ho)
{
    constexpr int G = CH / 8;
    const int t = blockIdx.x * 256 + threadIdx.x;
    const int cc = t & (G - 1);
    const int b = t / G;
    if (b >= Bc) return;
    const int so = blockIdx.y;
    const int ho = so / Ho, wo = so % Ho;
    float best[8];
#pragma unroll
    for (int e = 0; e < 8; ++e) best[e] = 0.f;
    for (int ph = 0; ph < 3; ++ph) {
        const int hh = 2 * ho - 1 + ph;
        if (hh < 0 || hh >= Hi) continue;
        for (int pw = 0; pw < 3; ++pw) {
            const int ww = 2 * wo - 1 + pw;
            if (ww < 0 || ww >= Hi) continue;
            const uint4 u = *(const uint4*)(src + ((long long)(hh * Hi + ww) * Bc + b) * CH + cc * 8);
            const u32 uw[4] = {u.x, u.y, u.z, u.w};
#pragma unroll
            for (int e = 0; e < 4; ++e) {
                best[2 * e]     = fmaxf(best[2 * e],     bf2f((u16)(uw[e] & 0xffff)));
                best[2 * e + 1] = fmaxf(best[2 * e + 1], bf2f((u16)(uw[e] >> 16)));
            }
        }
    }
    u32 pk[4];
#pragma unroll
    for (int e = 0; e < 4; ++e)
        pk[e] = (u32)f2bf(best[2 * e]) | (((u32)f2bf(best[2 * e + 1])) << 16);
    uint4 st;
    st.x = pk[0]; st.y = pk[1]; st.z = pk[2]; st.w = pk[3];
    *(uint4*)(dst + ((long long)so * Bc + b) * CH + cc * 8) = st;
}

// ---------------------------------------------------------------------------
// Head: logits(600->10)+softmax from h[n][Bc][640] bf16. n = blockIdx.y ->
// Wb accesses wave-uniform (s_loads).
// ---------------------------------------------------------------------------
template <int STAGE>
__global__ __launch_bounds__(256) void logits_softmax(
    const u16* __restrict__ h, const float* __restrict__ Wb, const float* __restrict__ bb,
    u16* __restrict__ preds, float* __restrict__ dout, int Bc, int gbase)
{
    const int b = blockIdx.x * 256 + threadIdx.x;
    const int n = blockIdx.y;
    const u16* hr = h + ((long long)n * Bc + b) * 640;
    const float* Wn = Wb + n * 6000;
    float acc[10];
#pragma unroll
    for (int j = 0; j < 10; ++j) acc[j] = bb[n * 10 + j];
    for (int c0 = 0; c0 < 600; c0 += 4) {
        const uint2 u = *(const uint2*)(hr + c0);
        float hv[4];
        hv[0] = bf2f((u16)(u.x & 0xffff));
        hv[1] = bf2f((u16)(u.x >> 16));
        hv[2] = bf2f((u16)(u.y & 0xffff));
        hv[3] = bf2f((u16)(u.y >> 16));
#pragma unroll
        for (int e = 0; e < 4; ++e)
#pragma unroll
            for (int j = 0; j < 10; ++j)
                acc[j] += hv[e] * Wn[(c0 + e) * 10 + j];
    }
    float mx = acc[0];
#pragma unroll
    for (int j = 1; j < 10; ++j) mx = fmaxf(mx, acc[j]);
    float p[10], ssum = 0.f;
#pragma unroll
    for (int j = 0; j < 10; ++j) { p[j] = __expf(acc[j] - mx); ssum += p[j]; }
    const float inv = 1.f / ssum;
    if (STAGE == 1) {
        u16* o = preds + ((long long)n * Bc + b) * 10;
#pragma unroll
        for (int j = 0; j < 10; ++j) o[j] = f2bf(p[j] * inv);
    } else {
        float* o = dout + 81920 + ((long long)n * 8192 + gbase + b) * 10;
#pragma unroll
        for (int j = 0; j < 10; ++j) o[j] = p[j] * inv;
    }
}

// ---------------------------------------------------------------------------
// Stage-2 input assembly.
// ---------------------------------------------------------------------------
__device__ __forceinline__ void neighbors5x5(int i, int* nb) {
    const int w = 5, size = 25;
    int cnt = 0;
    if (i - w >= 0) nb[cnt++] = i - w;
    if (i % w != 0) nb[cnt++] = i - 1;
    if ((i + 1) % w != 0) nb[cnt++] = i + 1;
    if (i + w < size) nb[cnt++] = i + w;
    if (i - w - 1 >= 0 && i % w != 0) nb[cnt++] = i - w - 1;
    if (i - w + 1 >= 0 && (i + 1) % w != 0) nb[cnt++] = i - w + 1;
    if (i + w - 1 < size && i % w != 0) nb[cnt++] = i + w - 1;
    if (i + w + 1 < size && (i + 1) % w != 0) nb[cnt++] = i + w + 1;
    for (; cnt < 8; ++cnt) nb[cnt] = -1;
}

__global__ __launch_bounds__(256) void gather_nb(
    const u16* __restrict__ preds, const u16* __restrict__ feats, u16* __restrict__ A2,
    int Bc, int bshift)
{
    const int g = blockIdx.x * 256 + threadIdx.x;  // n*Bc+b
    if (g >= 25 * Bc) return;
    const int n = g >> bshift;
    const int b = g & (Bc - 1);
    int nb[8];
    neighbors5x5(n, nb);
    u16* dst = A2 + (long long)g * 352;
#pragma unroll
    for (int j = 0; j < 8; ++j) {
        u32* d32 = (u32*)(dst + j * 10);
        if (nb[j] >= 0) {
            const u32* s32 = (const u32*)(preds + ((long long)nb[j] * Bc + b) * 10);
#pragma unroll
            for (int q = 0; q < 5; ++q) d32[q] = s32[q];
        } else {
#pragma unroll
            for (int q = 0; q < 5; ++q) d32[q] = 0u;
        }
    }
    const uint4* fs = (const uint4*)(feats + (long long)g * 256);
    uint4* fd = (uint4*)(dst + 80);
#pragma unroll
    for (int q = 0; q < 32; ++q) fd[q] = fs[q];
    uint4 z;
    z.x = 0u; z.y = 0u; z.z = 0u; z.w = 0u;
    *(uint4*)(dst + 336) = z;
    *(uint4*)(dst + 344) = z;
}

__global__ __launch_bounds__(256) void mean_k(float* __restrict__ dout)
{
    const int t = blockIdx.x * 256 + threadIdx.x;
    float s = 0.f;
#pragma unroll
    for (int n = 0; n < 25; ++n) s += dout[81920 + n * 81920 + t];
    dout[t] = s * 0.04f;
}

// ---------------------------------------------------------------------------
// Weight/param prep (once per launch)
// ---------------------------------------------------------------------------
__global__ void prep_bn_all(
    const float* b1, const float* g1, const float* be1, const float* m1, const float* v1,
    const float* b2, const float* g2, const float* be2, const float* m2, const float* v2,
    const float* b3, const float* g3, const float* be3, const float* m3, const float* v3,
    const float* b4, const float* g4, const float* be4, const float* m4, const float* v4,
    float* bnA, float* bnB)
{
    const int t = blockIdx.x * 256 + threadIdx.x;
    if (t >= 704) return;
    const float *bp, *gp, *bep, *mp, *vp;
    int idx;
    if (t < 64)       { bp=b1; gp=g1; bep=be1; mp=m1; vp=v1; idx=t; }
    else if (t < 192) { bp=b2; gp=g2; bep=be2; mp=m2; vp=v2; idx=t-64; }
    else if (t < 448) { bp=b3; gp=g3; bep=be3; mp=m3; vp=v3; idx=t-192; }
    else              { bp=b4; gp=g4; bep=be4; mp=m4; vp=v4; idx=t-448; }
    const float A = gp[idx] * rsqrtf(vp[idx] + 1e-5f);
    bnA[t] = A;
    bnB[t] = (bp[idx] - mp[idx]) * A + bep[idx];
}

// W1 [64][3][3][3] -> W1t [64][32], k = tap*3+ci (tap = kh*3+kw), pad 0
__global__ void prep_w1col(const float* __restrict__ W1, u16* __restrict__ W1t)
{
    const int t = blockIdx.x * 256 + threadIdx.x;
    if (t >= 64 * 32) return;
    const int n = t >> 5, k = t & 31;
    u16 v = 0;
    if (k < 27) {
        const int tap = k / 3, ci = k % 3;
        v = f2bf(W1[n * 27 + ci * 9 + tap]);
    }
    W1t[t] = v;
}

// W [Co][Ci][3][3] fp32 -> Wt [9][Co][Ci] bf16
__global__ void prep_convw(const float* __restrict__ W, u16* __restrict__ Wt, int Co, int Ci)
{
    const int t = blockIdx.x * 256 + threadIdx.x;
    const int tot = 9 * Co * Ci;
    if (t >= tot) return;
    const int sh = t / (Co * Ci);
    const int rem = t % (Co * Ci);
    const int co = rem / Ci, ci = rem % Ci;
    Wt[t] = f2bf(W[(long long)(co * Ci + ci) * 9 + sh]);
}

__global__ void prep_wat(const float* __restrict__ Wa, u16* __restrict__ Wat)
{
    const int t = blockIdx.x * 256 + threadIdx.x;
    if (t >= 25 * 640 * 352) return;
    const int n = t / (640 * 352);
    const int rem = t % (640 * 352);
    const int hcol = rem / 352;
    const int k = rem % 352;
    float v = 0.f;
    if (hcol < 600 && k < 336) v = Wa[((long long)n * 336 + k) * 600 + hcol];
    Wat[t] = f2bf(v);
}

__global__ void prep_ba(const float* __restrict__ ba, float* __restrict__ bap)
{
    const int t = blockIdx.x * 256 + threadIdx.x;
    if (t >= 25 * 640) return;
    const int n = t / 640, hcol = t % 640;
    bap[t] = (hcol < 600) ? ba[n * 600 + hcol] : 0.f;
}

// ---------------------------------------------------------------------------
extern "C" void kernel_launch(void* const* d_in, const int* in_sizes, int n_in,
                              void* d_out, int out_size, void* d_ws, size_t ws_size,
                              hipStream_t stream)
{
    (void)in_sizes; (void)n_in; (void)out_size;

    const float* x  = (const float*)d_in[0];
    const float* W1 = (const float*)d_in[1];
    const float* b1 = (const float*)d_in[2];
    const float* g1 = (const float*)d_in[3];
    const float* be1= (const float*)d_in[4];
    const float* m1 = (const float*)d_in[5];
    const float* v1 = (const float*)d_in[6];
    const float* W2 = (const float*)d_in[7];
    const float* b2 = (const float*)d_in[8];
    const float* g2 = (const float*)d_in[9];
    const float* be2= (const float*)d_in[10];
    const float* m2 = (const float*)d_in[11];
    const float* v2 = (const float*)d_in[12];
    const float* W3 = (const float*)d_in[13];
    const float* b3 = (const float*)d_in[14];
    const float* g3 = (const float*)d_in[15];
    const float* be3= (const float*)d_in[16];
    const float* m3 = (const float*)d_in[17];
    const float* v3 = (const float*)d_in[18];
    const float* W4 = (const float*)d_in[19];
    const float* b4 = (const float*)d_in[20];
    const float* g4 = (const float*)d_in[21];
    const float* be4= (const float*)d_in[22];
    const float* m4 = (const float*)d_in[23];
    const float* v4 = (const float*)d_in[24];
    const float* Wa = (const float*)d_in[25];
    const float* ba = (const float*)d_in[26];
    const float* Wb = (const float*)d_in[27];
    const float* bb = (const float*)d_in[28];
    float* dout = (float*)d_out;

    // ---- choose Bc: overlay peak = 80000 bytes per batch element ----
    auto al = [](long long v) { return (v + 255LL) & ~255LL; };
    const long long fixedB = al(4096) + al(147456) + al(589824) + al(1179648) +
                             al(11264000) + al(64000) + al(2816) + al(2816);
    int Bc = 256;
    for (int cand = 2048; cand >= 256; cand >>= 1) {
        long long need = fixedB + al(80000LL * cand);
        if (need <= (long long)ws_size) { Bc = cand; break; }
    }
    const int bshift = __builtin_ctz((unsigned)Bc);
    const int C = 8192 / Bc;

    // ---- workspace: fixed region + one overlaid chunk region ----
    char* wsp = (char*)d_ws;
    long long off = 0;
    auto alloc = [&](long long bytes) { long long o = off; off += al(bytes); return o; };
    u16* W1t  = (u16*)(wsp + alloc(4096));
    u16* Wt2  = (u16*)(wsp + alloc(147456));
    u16* Wt3  = (u16*)(wsp + alloc(589824));
    u16* Wt4  = (u16*)(wsp + alloc(1179648));
    u16* Wat  = (u16*)(wsp + alloc(11264000));
    float* bap = (float*)(wsp + alloc(64000));
    float* bnA = (float*)(wsp + alloc(2816));
    float* bnB = (float*)(wsp + alloc(2816));
    char* ch = wsp + alloc(80000LL * Bc);
    // overlay (bytes-per-elem offsets; lifetimes disjoint where ranges overlap):
    u16* xt   = (u16*)(ch + 0LL     * Bc);   // [0,3200)       t1-t1.5
    u16* xcol = (u16*)(ch + 3200LL  * Bc);   // [3200,28800)   t1.5-t2
    u16* a1   = (u16*)(ch + 28800LL * Bc);   // [28800,80000)  t2-t2.5
    u16* p1   = (u16*)(ch + 0LL     * Bc);   // [0,12800)      t2.5-t3
    u16* a2   = (u16*)(ch + 12800LL * Bc);   // [12800,38400)  t3-t3.5
    u16* p2   = (u16*)(ch + 38400LL * Bc);   // [38400,44800)  t3.5-t4
    u16* a3   = (u16*)(ch + 0LL     * Bc);   // [0,12800)      t4-t5
    u16* a4   = (u16*)(ch + 12800LL * Bc);   // [12800,25600)  t5-t8
    u16* h1   = (u16*)(ch + 25600LL * Bc);   // [25600,57600)  t6-t7
    u16* preds= (u16*)(ch + 57600LL * Bc);   // [57600,58100)  t7-t8
    u16* A2   = (u16*)(ch + 25600LL * Bc);   // [25600,43200)  t8-t9
    u16* h2   = (u16*)(ch + 43200LL * Bc);   // [43200,75200)  t9-t10

    // ---- prep (once) ----
    prep_bn_all<<<dim3(3), 256, 0, stream>>>(b1,g1,be1,m1,v1, b2,g2,be2,m2,v2,
                                             b3,g3,be3,m3,v3, b4,g4,be4,m4,v4, bnA, bnB);
    prep_w1col<<<dim3(8), 256, 0, stream>>>(W1, W1t);
    prep_convw<<<dim3(288),  256, 0, stream>>>(W2, Wt2, 128, 64);
    prep_convw<<<dim3(1152), 256, 0, stream>>>(W3, Wt3, 256, 128);
    prep_convw<<<dim3(2304), 256, 0, stream>>>(W4, Wt4, 256, 256);
    prep_wat<<<dim3(22000), 256, 0, stream>>>(Wa, Wat);
    prep_ba<<<dim3(63), 256, 0, stream>>>(ba, bap);

    // ---- batch chunks ----
    for (int c = 0; c < C; ++c) {
        const float* xc = x + (long long)c * Bc * 1200;

        transpose_x<<<dim3(400 * Bc / 256), 256, 0, stream>>>(xc, xt, Bc, bshift);
        im2col1<<<dim3(400 * Bc / 256), 256, 0, stream>>>(xt, xcol, Bc, bshift);
        // conv1: flat M = 400*Bc, N=64, K=32 (one k-step), relu+bn epilogue
        gemm_bt<0,64><<<dim3(400 * Bc / 128, 1), 256, 0, stream>>>(xcol, W1t, a1, bnA, bnB,
            32, 64, 1, 1, 1, 32, 32, 64, 0LL, 0LL, 0LL, 0, Bc, bshift);
        pool_k<64><<<dim3(Bc * 8 / 256, 100), 256, 0, stream>>>(a1, p1, Bc, 20, 10);

        gemm_bt<0,128><<<dim3(100 * Bc / 128, 1), 256, 0, stream>>>(p1, Wt2, a2, bnA + 64, bnB + 64,
            64, 128, 9, 10, 10, 64, 64, 128, 0LL, 0LL, 0LL, 0, Bc, bshift);
        pool_k<128><<<dim3(Bc * 16 / 256, 25), 256, 0, stream>>>(a2, p2, Bc, 10, 5);

        gemm_bt<0,128><<<dim3(25 * Bc / 128, 2), 256, 0, stream>>>(p2, Wt3, a3, bnA + 192, bnB + 192,
            128, 256, 9, 5, 5, 128, 128, 256, 0LL, 0LL, 0LL, 0, Bc, bshift);
        gemm_bt<0,128><<<dim3(25 * Bc / 128, 2), 256, 0, stream>>>(a3, Wt4, a4, bnA + 448, bnB + 448,
            256, 256, 9, 5, 5, 256, 256, 256, 0LL, 0LL, 0LL, 0, Bc, bshift);

        // stage 1 MLP: zeros||feats -> only k-rows [80:336) of Wa matter
        gemm_bt<1,128><<<dim3(Bc / 128, 5, 25), 256, 0, stream>>>(a4, Wat + 80, h1, nullptr, bap,
            256, 640, 1, 1, 1, 256, 352, 640,
            (long long)Bc * 256, 640LL * 352, (long long)Bc * 640, 640, Bc, bshift);
        logits_softmax<1><<<dim3(Bc / 256, 25), 256, 0, stream>>>(
            h1, Wb, bb, preds, nullptr, Bc, 0);

        // stage 2
        gather_nb<<<dim3(25 * Bc / 256, 1), 256, 0, stream>>>(preds, a4, A2, Bc, bshift);
        gemm_bt<1,128><<<dim3(Bc / 128, 5, 25), 256, 0, stream>>>(A2, Wat, h2, nullptr, bap,
            352, 640, 1, 1, 1, 352, 352, 640,
            (long long)Bc * 352, 640LL * 352, (long long)Bc * 640, 640, Bc, bshift);
        logits_softmax<2><<<dim3(Bc / 256, 25), 256, 0, stream>>>(
            h2, Wb, bb, nullptr, dout, Bc, c * Bc);
    }

    mean_k<<<dim3(320), 256, 0, stream>>>(dout);
}

// Round 5
// 1717.623 us; speedup vs baseline: 1.4150x; 1.2020x over previous
//
#include <hip/hip_runtime.h>

typedef unsigned short u16;
typedef unsigned int u32;

typedef __attribute__((ext_vector_type(8))) __bf16 bf16x8;
typedef __attribute__((ext_vector_type(4))) float f32x4;

__device__ __forceinline__ float bf2f(u16 u) {
    u32 t = ((u32)u) << 16;
    float f;
    __builtin_memcpy(&f, &t, 4);
    return f;
}
__device__ __forceinline__ u16 f2bf(float f) {
    u32 u;
    __builtin_memcpy(&u, &f, 4);
    u32 r = (u + 0x7fffu + ((u >> 16) & 1u)) >> 16;
    return (u16)r;
}
__device__ __forceinline__ float tanh_fast(float x) {
    float xc = fminf(fmaxf(x, -15.f), 15.f);
    float e = __expf(2.f * xc);
    return (e - 1.f) / (e + 1.f);
}

// Async global->LDS DMA, 16B per lane. LDS dest = wave-uniform base + lane*16.
__device__ __forceinline__ void gld16(const u16* g, u16* l) {
    __builtin_amdgcn_global_load_lds(
        (const __attribute__((address_space(1))) u32*)(uintptr_t)g,
        (__attribute__((address_space(3))) u32*)(u32)(uintptr_t)l,
        16, 0, 0);
}

// LDS bank swizzle (round 5): gld16 pins LDS slot = lane*16, but the GLOBAL
// address per lane is free. Chunk c (16B) of row r is staged into slot
// (c + (r>>1)) & 3 of that row; consumer reads chunk qd of row R at
// csel = (qd + (R>>1)) & 3. Every consecutive-8-lane group of the b128 reads
// then covers all eight 16B bank-groups -> conflict-free (old layout: 4-way).
// Staged-side: lane (srow=lane>>2, j=lane&3) must fetch global chunk
// c = (j - (srow>>1)) & 3.  Consumer-side csel reduces to (qd + (ln>>1)) & 3
// because all row-base terms (mbase, f*16, wave*32, slab +16) are ≡0 mod 8.

// ---------------------------------------------------------------------------
// bf16 MFMA GEMM, tile 128 x NT:  C[m,n] (+)= sum_t sum_k A_t[m,k]*W_t[n,k]
// A: [spatial][Bc][ldA] (k-contiguous). W: [T][N][ldW]. T==9 -> 3x3 conv via
// shift-GEMM, invalid shifts skipped (block-uniform: tile sits at one spatial
// position). 4 waves: 2x2 partition; NT=128 -> 64x64/wave, NT=64 -> 64x32/wave.
// EPI 0: relu(acc*epiA[n]+epiB[n]); EPI 1: tanh(acc+epiB[n]).
// ---------------------------------------------------------------------------
template <int EPI, int NT>
__global__ __launch_bounds__(256, 3) void gemm_bt(
    const u16* __restrict__ A, const u16* __restrict__ W, u16* __restrict__ O,
    const float* __restrict__ epiA, const float* __restrict__ epiB,
    int Kin, int N, int T, int Himg, int Wimg,
    int ldA, int ldW, int ldO,
    long long Az, long long Wz, long long Oz, int epiZ,
    int Bc, int bshift)
{
    constexpr int NJ = NT / 32;          // 4 (NT=128) or 2 (NT=64)
    __shared__ __align__(16) u16 lsA[128 * 32];
    __shared__ __align__(16) u16 lsW[NT * 32];

    const int tid = threadIdx.x;
    const int z = blockIdx.z;
    A += (long long)z * Az;
    W += (long long)z * Wz;
    O += (long long)z * Oz;
    epiB += (long long)z * epiZ;

    const int m0 = blockIdx.x * 128;
    const int n0 = blockIdx.y * NT;
    const int s = m0 >> bshift;          // spatial index (chunk row for flat-M)
    const int b0 = m0 & (Bc - 1);        // batch offset
    const int hh0 = s / Wimg, ww0 = s % Wimg;

    const int wave = tid >> 6;
    const int lane = tid & 63;
    const int mbase = (wave >> 1) * 64;
    const int nbase = (wave & 1) * (NT / 2);
    const int ln = lane & 15, qd = lane >> 4;

    const int srow = lane >> 2;                               // staging row in 16-slab
    const int sc = (((lane & 3) - ((srow >> 1) & 3)) & 3) * 8; // swizzled fetch chunk
    const int csel = ((qd + (ln >> 1)) & 3) * 8;               // swizzled read chunk

    f32x4 acc[4][NJ];
#pragma unroll
    for (int i = 0; i < 4; ++i)
#pragma unroll
        for (int j = 0; j < NJ; ++j)
            acc[i][j] = (f32x4){0.f, 0.f, 0.f, 0.f};

    for (int t = 0; t < T; ++t) {
        int sp;
        if (T == 9) {
            int hh = hh0 + t / 3 - 1;
            int ww = ww0 + t % 3 - 1;
            if (hh < 0 || hh >= Himg || ww < 0 || ww >= Wimg) continue;  // block-uniform
            sp = hh * Wimg + ww;
        } else {
            sp = s;
        }
        const u16* At = A + (long long)(sp * Bc + b0) * ldA;
        const u16* Wt = W + ((long long)t * N + n0) * ldW;
        const u16* gA0 = At + (long long)(wave * 32 + srow) * ldA + sc;
        const u16* gA1 = gA0 + 16 * ldA;
        u16* lA0 = lsA + wave * 1024;
        u16* lA1 = lA0 + 512;
        const u16* gW0;
        u16* lW0;
        if (NT == 128) {
            gW0 = Wt + (long long)(wave * 32 + srow) * ldW + sc;
            lW0 = lsW + wave * 1024;
        } else {
            gW0 = Wt + (long long)(wave * 16 + srow) * ldW + sc;
            lW0 = lsW + wave * 512;
        }
        const u16* gW1 = gW0 + 16 * ldW;   // NT==128 only
        u16* lW1 = lW0 + 512;

        for (int k0 = 0; k0 < Kin; k0 += 32) {
            __syncthreads();                 // prev iter's LDS fully consumed
            gld16(gA0 + k0, lA0);
            gld16(gA1 + k0, lA1);
            gld16(gW0 + k0, lW0);
            if (NT == 128) gld16(gW1 + k0, lW1);
            __syncthreads();                 // drains vmcnt -> LDS ready

            bf16x8 af[4], bfr[NJ];
#pragma unroll
            for (int f = 0; f < 4; ++f)
                af[f] = *(const bf16x8*)&lsA[(mbase + f * 16 + ln) * 32 + csel];
#pragma unroll
            for (int f = 0; f < NJ; ++f)
                bfr[f] = *(const bf16x8*)&lsW[(nbase + f * 16 + ln) * 32 + csel];
#pragma unroll
            for (int i = 0; i < 4; ++i)
#pragma unroll
                for (int j = 0; j < NJ; ++j)
                    acc[i][j] = __builtin_amdgcn_mfma_f32_16x16x32_bf16(
                        af[i], bfr[j], acc[i][j], 0, 0, 0);
        }
    }

#pragma unroll
    for (int j = 0; j < NJ; ++j) {
        const int n = n0 + nbase + j * 16 + ln;
        const float sh = epiB[n];
        float sc2 = 1.f;
        if (EPI == 0) sc2 = epiA[n];
#pragma unroll
        for (int i = 0; i < 4; ++i) {
            const int mrow = mbase + i * 16 + qd * 4;
#pragma unroll
            for (int rr = 0; rr < 4; ++rr) {
                float v = acc[i][j][rr];
                if (EPI == 0) v = fmaxf(v * sc2 + sh, 0.f);
                else          v = tanh_fast(v + sh);
                O[(long long)(m0 + mrow + rr) * ldO + n] = f2bf(v);
            }
        }
    }
}

// ---------------------------------------------------------------------------
// Logits(600->10, padded 640->16) + softmax via MFMA.
// h[n][Bc][640] bf16 (pad cols 600..639 are exactly 0), Wbp[n][16][640] bf16
// (pad zeros), bbp[n][16] fp32 (pad -1e30 -> exp=0, no lane masking needed).
// Block: M-tile 128 (batch), wave w handles rows w*32..+32 (2 m-frags), K=640.
// C layout: col=ln, row=qd*4+rr -> softmax = shfl-xor reduce over 16-lane group.
// STAGE 1 -> preds bf16 [25][Bc][10]; STAGE 2 -> d_out fp32.
// ---------------------------------------------------------------------------
template <int STAGE>
__global__ __launch_bounds__(256) void logits_mfma(
    const u16* __restrict__ h, const u16* __restrict__ Wbp, const float* __restrict__ bbp,
    u16* __restrict__ preds, float* __restrict__ dout, int Bc, int gbase)
{
    __shared__ __align__(16) u16 lsA[128 * 32];
    __shared__ __align__(16) u16 lsW[16 * 32];

    const int tid = threadIdx.x;
    const int n = blockIdx.y;
    const int m0 = blockIdx.x * 128;
    const u16* A = h + ((long long)n * Bc + m0) * 640;
    const u16* Wn = Wbp + n * 16 * 640;

    const int wave = tid >> 6;
    const int lane = tid & 63;
    const int ln = lane & 15, qd = lane >> 4;
    const int srow = lane >> 2;
    const int sc = (((lane & 3) - ((srow >> 1) & 3)) & 3) * 8;
    const int csel = ((qd + (ln >> 1)) & 3) * 8;

    const u16* gA0 = A + (long long)(wave * 32 + srow) * 640 + sc;
    const u16* gA1 = gA0 + 16 * 640;
    u16* lA0 = lsA + wave * 1024;
    u16* lA1 = lA0 + 512;
    const u16* gW0 = Wn + srow * 640 + sc;   // staged by wave 0 only

    f32x4 acc[2];
    acc[0] = (f32x4){0.f, 0.f, 0.f, 0.f};
    acc[1] = (f32x4){0.f, 0.f, 0.f, 0.f};

    for (int k0 = 0; k0 < 640; k0 += 32) {
        __syncthreads();
        gld16(gA0 + k0, lA0);
        gld16(gA1 + k0, lA1);
        if (wave == 0) gld16(gW0 + k0, lsW);
        __syncthreads();
        const bf16x8 bfr = *(const bf16x8*)&lsW[ln * 32 + csel];
        const bf16x8 a0 = *(const bf16x8*)&lsA[(wave * 32 + ln) * 32 + csel];
        const bf16x8 a1 = *(const bf16x8*)&lsA[(wave * 32 + 16 + ln) * 32 + csel];
        acc[0] = __builtin_amdgcn_mfma_f32_16x16x32_bf16(a0, bfr, acc[0], 0, 0, 0);
        acc[1] = __builtin_amdgcn_mfma_f32_16x16x32_bf16(a1, bfr, acc[1], 0, 0, 0);
    }

    const float bias = bbp[n * 16 + ln];
#pragma unroll
    for (int i = 0; i < 2; ++i) {
#pragma unroll
        for (int rr = 0; rr < 4; ++rr) {
            const float v = acc[i][rr] + bias;
            float mx = v;
#pragma unroll
            for (int mk = 1; mk < 16; mk <<= 1)
                mx = fmaxf(mx, __shfl_xor(mx, mk));
            const float e = __expf(v - mx);
            float ssum = e;
#pragma unroll
            for (int mk = 1; mk < 16; mk <<= 1)
                ssum += __shfl_xor(ssum, mk);
            const float p = e / ssum;
            const int row = m0 + wave * 32 + i * 16 + qd * 4 + rr;
            if (ln < 10) {
                if (STAGE == 1)
                    preds[((long long)n * Bc + row) * 10 + ln] = f2bf(p);
                else
                    dout[81920 + ((long long)n * 8192 + gbase + row) * 10 + ln] = p;
            }
        }
    }
}

// ---------------------------------------------------------------------------
// x chunk [Bc,3,20,20] fp32 -> xt [400][Bc][4] bf16 (ch padded to 4, pad=0)
// ---------------------------------------------------------------------------
__global__ __launch_bounds__(256) void transpose_x(
    const float* __restrict__ x, u16* __restrict__ xt, int Bc, int bshift)
{
    const int t = blockIdx.x * 256 + threadIdx.x;
    if (t >= 400 * Bc) return;
    const int s = t >> bshift;
    const int b = t & (Bc - 1);
    const u32 c0 = f2bf(x[((long long)b * 3 + 0) * 400 + s]);
    const u32 c1 = f2bf(x[((long long)b * 3 + 1) * 400 + s]);
    const u32 c2 = f2bf(x[((long long)b * 3 + 2) * 400 + s]);
    uint2 st;
    st.x = c0 | (c1 << 16);
    st.y = c2;                              // high 16 = 0 pad
    *(uint2*)(xt + ((long long)s * Bc + b) * 4) = st;
}

// ---------------------------------------------------------------------------
// im2col for conv1: xt[400][Bc][4] -> xcol[400][Bc][32] (k = tap*3+ci, pad 0).
// Pure scalars (no private arrays -> no scratch). s is block-uniform.
// ---------------------------------------------------------------------------
__global__ __launch_bounds__(256) void im2col1(
    const u16* __restrict__ xt, u16* __restrict__ xcol, int Bc, int bshift)
{
    const int t = blockIdx.x * 256 + threadIdx.x;
    if (t >= 400 * Bc) return;
    const int s = t >> bshift;
    const int b = t & (Bc - 1);
    const int hh = s / 20, ww = s % 20;

    u32 p0, q0, p1, q1, p2, q2, p3, q3, p4, q4, p5, q5, p6, q6, p7, q7, p8, q8;
#define LOADTAP(T, P, Q)                                                      \
    {                                                                         \
        const int ih = hh + (T) / 3 - 1, iw = ww + (T) % 3 - 1;               \
        P = 0u; Q = 0u;                                                       \
        if (ih >= 0 && ih < 20 && iw >= 0 && iw < 20) {                       \
            const uint2 v = *(const uint2*)(xt +                              \
                ((long long)(ih * 20 + iw) * Bc + b) * 4);                    \
            P = v.x; Q = v.y;                                                 \
        }                                                                     \
    }
    LOADTAP(0, p0, q0) LOADTAP(1, p1, q1) LOADTAP(2, p2, q2)
    LOADTAP(3, p3, q3) LOADTAP(4, p4, q4) LOADTAP(5, p5, q5)
    LOADTAP(6, p6, q6) LOADTAP(7, p7, q7) LOADTAP(8, p8, q8)
#undef LOADTAP

    u16* o = xcol + (long long)t * 32;
    uint4 w;
    w.x = p0;                w.y = q0 | (p1 << 16);
    w.z = (p1 >> 16) | (q1 << 16);
    w.w = p2;
    *(uint4*)(o + 0) = w;
    w.x = q2 | (p3 << 16);   w.y = (p3 >> 16) | (q3 << 16);
    w.z = p4;                w.w = q4 | (p5 << 16);
    *(uint4*)(o + 8) = w;
    w.x = (p5 >> 16) | (q5 << 16);
    w.y = p6;                w.z = q6 | (p7 << 16);
    w.w = (p7 >> 16) | (q7 << 16);
    *(uint4*)(o + 16) = w;
    w.x = p8;                w.y = q8;   // k=24..26 (+pad)
    w.z = 0u;                w.w = 0u;
    *(uint4*)(o + 24) = w;
}

// ---------------------------------------------------------------------------
// maxpool 3x3 s2 p1, square maps: src[Hi*Hi][Bc][CH] -> dst[Ho*Ho][Bc][CH].
// Values already relu'd (>= 0) so pool floor = 0.
// ---------------------------------------------------------------------------
template <int CH>
__global__ __launch_bounds__(256) void pool_k(
    const u16* __restrict__ src, u16* __restrict__ dst, int Bc, int Hi, int Ho)
{
    constexpr int G = CH / 8;
    const int t = blockIdx.x * 256 + threadIdx.x;
    const int cc = t & (G - 1);
    const int b = t / G;
    if (b >= Bc) return;
    const int so = blockIdx.y;
    const int ho = so / Ho, wo = so % Ho;
    float best[8];
#pragma unroll
    for (int e = 0; e < 8; ++e) best[e] = 0.f;
    for (int ph = 0; ph < 3; ++ph) {
        const int hh = 2 * ho - 1 + ph;
        if (hh < 0 || hh >= Hi) continue;
        for (int pw = 0; pw < 3; ++pw) {
            const int ww = 2 * wo - 1 + pw;
            if (ww < 0 || ww >= Hi) continue;
            const uint4 u = *(const uint4*)(src + ((long long)(hh * Hi + ww) * Bc + b) * CH + cc * 8);
            const u32 uw[4] = {u.x, u.y, u.z, u.w};
#pragma unroll
            for (int e = 0; e < 4; ++e) {
                best[2 * e]     = fmaxf(best[2 * e],     bf2f((u16)(uw[e] & 0xffff)));
                best[2 * e + 1] = fmaxf(best[2 * e + 1], bf2f((u16)(uw[e] >> 16)));
            }
        }
    }
    u32 pk[4];
#pragma unroll
    for (int e = 0; e < 4; ++e)
        pk[e] = (u32)f2bf(best[2 * e]) | (((u32)f2bf(best[2 * e + 1])) << 16);
    uint4 st;
    st.x = pk[0]; st.y = pk[1]; st.z = pk[2]; st.w = pk[3];
    *(uint4*)(dst + ((long long)so * Bc + b) * CH + cc * 8) = st;
}

// ---------------------------------------------------------------------------
// Stage-2 input assembly.
// ---------------------------------------------------------------------------
__device__ __forceinline__ void neighbors5x5(int i, int* nb) {
    const int w = 5, size = 25;
    int cnt = 0;
    if (i - w >= 0) nb[cnt++] = i - w;
    if (i % w != 0) nb[cnt++] = i - 1;
    if ((i + 1) % w != 0) nb[cnt++] = i + 1;
    if (i + w < size) nb[cnt++] = i + w;
    if (i - w - 1 >= 0 && i % w != 0) nb[cnt++] = i - w - 1;
    if (i - w + 1 >= 0 && (i + 1) % w != 0) nb[cnt++] = i - w + 1;
    if (i + w - 1 < size && i % w != 0) nb[cnt++] = i + w - 1;
    if (i + w + 1 < size && (i + 1) % w != 0) nb[cnt++] = i + w + 1;
    for (; cnt < 8; ++cnt) nb[cnt] = -1;
}

__global__ __launch_bounds__(256) void gather_nb(
    const u16* __restrict__ preds, const u16* __restrict__ feats, u16* __restrict__ A2,
    int Bc, int bshift)
{
    const int g = blockIdx.x * 256 + threadIdx.x;  // n*Bc+b
    if (g >= 25 * Bc) return;
    const int n = g >> bshift;
    const int b = g & (Bc - 1);
    int nb[8];
    neighbors5x5(n, nb);
    u16* dst = A2 + (long long)g * 352;
#pragma unroll
    for (int j = 0; j < 8; ++j) {
        u32* d32 = (u32*)(dst + j * 10);
        if (nb[j] >= 0) {
            const u32* s32 = (const u32*)(preds + ((long long)nb[j] * Bc + b) * 10);
#pragma unroll
            for (int q = 0; q < 5; ++q) d32[q] = s32[q];
        } else {
#pragma unroll
            for (int q = 0; q < 5; ++q) d32[q] = 0u;
        }
    }
    const uint4* fs = (const uint4*)(feats + (long long)g * 256);
    uint4* fd = (uint4*)(dst + 80);
#pragma unroll
    for (int q = 0; q < 32; ++q) fd[q] = fs[q];
    uint4 z;
    z.x = 0u; z.y = 0u; z.z = 0u; z.w = 0u;
    *(uint4*)(dst + 336) = z;
    *(uint4*)(dst + 344) = z;
}

__global__ __launch_bounds__(256) void mean_k(float* __restrict__ dout)
{
    const int t = blockIdx.x * 256 + threadIdx.x;
    float s = 0.f;
#pragma unroll
    for (int n = 0; n < 25; ++n) s += dout[81920 + n * 81920 + t];
    dout[t] = s * 0.04f;
}

// ---------------------------------------------------------------------------
// Weight/param prep (once per launch)
// ---------------------------------------------------------------------------
__global__ void prep_bn_all(
    const float* b1, const float* g1, const float* be1, const float* m1, const float* v1,
    const float* b2, const float* g2, const float* be2, const float* m2, const float* v2,
    const float* b3, const float* g3, const float* be3, const float* m3, const float* v3,
    const float* b4, const float* g4, const float* be4, const float* m4, const float* v4,
    float* bnA, float* bnB)
{
    const int t = blockIdx.x * 256 + threadIdx.x;
    if (t >= 704) return;
    const float *bp, *gp, *bep, *mp, *vp;
    int idx;
    if (t < 64)       { bp=b1; gp=g1; bep=be1; mp=m1; vp=v1; idx=t; }
    else if (t < 192) { bp=b2; gp=g2; bep=be2; mp=m2; vp=v2; idx=t-64; }
    else if (t < 448) { bp=b3; gp=g3; bep=be3; mp=m3; vp=v3; idx=t-192; }
    else              { bp=b4; gp=g4; bep=be4; mp=m4; vp=v4; idx=t-448; }
    const float A = gp[idx] * rsqrtf(vp[idx] + 1e-5f);
    bnA[t] = A;
    bnB[t] = (bp[idx] - mp[idx]) * A + bep[idx];
}

// W1 [64][3][3][3] -> W1t [64][32], k = tap*3+ci (tap = kh*3+kw), pad 0
__global__ void prep_w1col(const float* __restrict__ W1, u16* __restrict__ W1t)
{
    const int t = blockIdx.x * 256 + threadIdx.x;
    if (t >= 64 * 32) return;
    const int n = t >> 5, k = t & 31;
    u16 v = 0;
    if (k < 27) {
        const int tap = k / 3, ci = k % 3;
        v = f2bf(W1[n * 27 + ci * 9 + tap]);
    }
    W1t[t] = v;
}

// W [Co][Ci][3][3] fp32 -> Wt [9][Co][Ci] bf16
__global__ void prep_convw(const float* __restrict__ W, u16* __restrict__ Wt, int Co, int Ci)
{
    const int t = blockIdx.x * 256 + threadIdx.x;
    const int tot = 9 * Co * Ci;
    if (t >= tot) return;
    const int sh = t / (Co * Ci);
    const int rem = t % (Co * Ci);
    const int co = rem / Ci, ci = rem % Ci;
    Wt[t] = f2bf(W[(long long)(co * Ci + ci) * 9 + sh]);
}

__global__ void prep_wat(const float* __restrict__ Wa, u16* __restrict__ Wat)
{
    const int t = blockIdx.x * 256 + threadIdx.x;
    if (t >= 25 * 640 * 352) return;
    const int n = t / (640 * 352);
    const int rem = t % (640 * 352);
    const int hcol = rem / 352;
    const int k = rem % 352;
    float v = 0.f;
    if (hcol < 600 && k < 336) v = Wa[((long long)n * 336 + k) * 600 + hcol];
    Wat[t] = f2bf(v);
}

__global__ void prep_ba(const float* __restrict__ ba, float* __restrict__ bap)
{
    const int t = blockIdx.x * 256 + threadIdx.x;
    if (t >= 25 * 640) return;
    const int n = t / 640, hcol = t % 640;
    bap[t] = (hcol < 600) ? ba[n * 600 + hcol] : 0.f;
}

// Wb [25][600][10] fp32 -> Wbp [25][16][640] bf16 (transposed, zero-pad);
// bb [25][10] -> bbp [25][16] fp32 (pad -1e30 so softmax ignores pad cols)
__global__ void prep_wbt(const float* __restrict__ Wb, const float* __restrict__ bb,
                         u16* __restrict__ Wbp, float* __restrict__ bbp)
{
    const int t = blockIdx.x * 256 + threadIdx.x;
    if (t < 25 * 16 * 640) {
        const int n = t / (16 * 640);
        const int rem = t % (16 * 640);
        const int c = rem / 640, k = rem % 640;
        u16 v = 0;
        if (c < 10 && k < 600) v = f2bf(Wb[((long long)n * 600 + k) * 10 + c]);
        Wbp[t] = v;
    }
    if (t < 25 * 16) {
        const int n = t >> 4, c = t & 15;
        bbp[t] = (c < 10) ? bb[n * 10 + c] : -1e30f;
    }
}

// ---------------------------------------------------------------------------
extern "C" void kernel_launch(void* const* d_in, const int* in_sizes, int n_in,
                              void* d_out, int out_size, void* d_ws, size_t ws_size,
                              hipStream_t stream)
{
    (void)in_sizes; (void)n_in; (void)out_size;

    const float* x  = (const float*)d_in[0];
    const float* W1 = (const float*)d_in[1];
    const float* b1 = (const float*)d_in[2];
    const float* g1 = (const float*)d_in[3];
    const float* be1= (const float*)d_in[4];
    const float* m1 = (const float*)d_in[5];
    const float* v1 = (const float*)d_in[6];
    const float* W2 = (const float*)d_in[7];
    const float* b2 = (const float*)d_in[8];
    const float* g2 = (const float*)d_in[9];
    const float* be2= (const float*)d_in[10];
    const float* m2 = (const float*)d_in[11];
    const float* v2 = (const float*)d_in[12];
    const float* W3 = (const float*)d_in[13];
    const float* b3 = (const float*)d_in[14];
    const float* g3 = (const float*)d_in[15];
    const float* be3= (const float*)d_in[16];
    const float* m3 = (const float*)d_in[17];
    const float* v3 = (const float*)d_in[18];
    const float* W4 = (const float*)d_in[19];
    const float* b4 = (const float*)d_in[20];
    const float* g4 = (const float*)d_in[21];
    const float* be4= (const float*)d_in[22];
    const float* m4 = (const float*)d_in[23];
    const float* v4 = (const float*)d_in[24];
    const float* Wa = (const float*)d_in[25];
    const float* ba = (const float*)d_in[26];
    const float* Wb = (const float*)d_in[27];
    const float* bb = (const float*)d_in[28];
    float* dout = (float*)d_out;

    // ---- choose Bc: overlay peak = 80000 bytes per batch element ----
    auto al = [](long long v) { return (v + 255LL) & ~255LL; };
    const long long fixedB = al(4096) + al(147456) + al(589824) + al(1179648) +
                             al(11264000) + al(64000) + al(2816) + al(2816) +
                             al(512000) + al(1600);
    int Bc = 256;
    for (int cand = 2048; cand >= 256; cand >>= 1) {
        long long need = fixedB + al(80000LL * cand);
        if (need <= (long long)ws_size) { Bc = cand; break; }
    }
    const int bshift = __builtin_ctz((unsigned)Bc);
    const int C = 8192 / Bc;

    // ---- workspace: fixed region + one overlaid chunk region ----
    char* wsp = (char*)d_ws;
    long long off = 0;
    auto alloc = [&](long long bytes) { long long o = off; off += al(bytes); return o; };
    u16* W1t  = (u16*)(wsp + alloc(4096));
    u16* Wt2  = (u16*)(wsp + alloc(147456));
    u16* Wt3  = (u16*)(wsp + alloc(589824));
    u16* Wt4  = (u16*)(wsp + alloc(1179648));
    u16* Wat  = (u16*)(wsp + alloc(11264000));
    float* bap = (float*)(wsp + alloc(64000));
    float* bnA = (float*)(wsp + alloc(2816));
    float* bnB = (float*)(wsp + alloc(2816));
    u16* Wbp  = (u16*)(wsp + alloc(512000));
    float* bbp = (float*)(wsp + alloc(1600));
    char* ch = wsp + alloc(80000LL * Bc);
    // overlay (bytes-per-elem offsets; lifetimes disjoint where ranges overlap):
    u16* xt   = (u16*)(ch + 0LL     * Bc);   // [0,3200)       t1-t1.5
    u16* xcol = (u16*)(ch + 3200LL  * Bc);   // [3200,28800)   t1.5-t2
    u16* a1   = (u16*)(ch + 28800LL * Bc);   // [28800,80000)  t2-t2.5
    u16* p1   = (u16*)(ch + 0LL     * Bc);   // [0,12800)      t2.5-t3
    u16* a2   = (u16*)(ch + 12800LL * Bc);   // [12800,38400)  t3-t3.5
    u16* p2   = (u16*)(ch + 38400LL * Bc);   // [38400,44800)  t3.5-t4
    u16* a3   = (u16*)(ch + 0LL     * Bc);   // [0,12800)      t4-t5
    u16* a4   = (u16*)(ch + 12800LL * Bc);   // [12800,25600)  t5-t8
    u16* h1   = (u16*)(ch + 25600LL * Bc);   // [25600,57600)  t6-t7
    u16* preds= (u16*)(ch + 57600LL * Bc);   // [57600,58100)  t7-t8
    u16* A2   = (u16*)(ch + 25600LL * Bc);   // [25600,43200)  t8-t9
    u16* h2   = (u16*)(ch + 43200LL * Bc);   // [43200,75200)  t9-t10

    // ---- prep (once) ----
    prep_bn_all<<<dim3(3), 256, 0, stream>>>(b1,g1,be1,m1,v1, b2,g2,be2,m2,v2,
                                             b3,g3,be3,m3,v3, b4,g4,be4,m4,v4, bnA, bnB);
    prep_w1col<<<dim3(8), 256, 0, stream>>>(W1, W1t);
    prep_convw<<<dim3(288),  256, 0, stream>>>(W2, Wt2, 128, 64);
    prep_convw<<<dim3(1152), 256, 0, stream>>>(W3, Wt3, 256, 128);
    prep_convw<<<dim3(2304), 256, 0, stream>>>(W4, Wt4, 256, 256);
    prep_wat<<<dim3(22000), 256, 0, stream>>>(Wa, Wat);
    prep_ba<<<dim3(63), 256, 0, stream>>>(ba, bap);
    prep_wbt<<<dim3(1000), 256, 0, stream>>>(Wb, bb, Wbp, bbp);

    // ---- batch chunks ----
    for (int c = 0; c < C; ++c) {
        const float* xc = x + (long long)c * Bc * 1200;

        transpose_x<<<dim3(400 * Bc / 256), 256, 0, stream>>>(xc, xt, Bc, bshift);
        im2col1<<<dim3(400 * Bc / 256), 256, 0, stream>>>(xt, xcol, Bc, bshift);
        // conv1: flat M = 400*Bc, N=64, K=32 (one k-step), relu+bn epilogue
        gemm_bt<0,64><<<dim3(400 * Bc / 128, 1), 256, 0, stream>>>(xcol, W1t, a1, bnA, bnB,
            32, 64, 1, 1, 1, 32, 32, 64, 0LL, 0LL, 0LL, 0, Bc, bshift);
        pool_k<64><<<dim3(Bc * 8 / 256, 100), 256, 0, stream>>>(a1, p1, Bc, 20, 10);

        gemm_bt<0,128><<<dim3(100 * Bc / 128, 1), 256, 0, stream>>>(p1, Wt2, a2, bnA + 64, bnB + 64,
            64, 128, 9, 10, 10, 64, 64, 128, 0LL, 0LL, 0LL, 0, Bc, bshift);
        pool_k<128><<<dim3(Bc * 16 / 256, 25), 256, 0, stream>>>(a2, p2, Bc, 10, 5);

        gemm_bt<0,128><<<dim3(25 * Bc / 128, 2), 256, 0, stream>>>(p2, Wt3, a3, bnA + 192, bnB + 192,
            128, 256, 9, 5, 5, 128, 128, 256, 0LL, 0LL, 0LL, 0, Bc, bshift);
        gemm_bt<0,128><<<dim3(25 * Bc / 128, 2), 256, 0, stream>>>(a3, Wt4, a4, bnA + 448, bnB + 448,
            256, 256, 9, 5, 5, 256, 256, 256, 0LL, 0LL, 0LL, 0, Bc, bshift);

        // stage 1 MLP: zeros||feats -> only k-rows [80:336) of Wa matter
        gemm_bt<1,128><<<dim3(Bc / 128, 5, 25), 256, 0, stream>>>(a4, Wat + 80, h1, nullptr, bap,
            256, 640, 1, 1, 1, 256, 352, 640,
            (long long)Bc * 256, 640LL * 352, (long long)Bc * 640, 640, Bc, bshift);
        logits_mfma<1><<<dim3(Bc / 128, 25), 256, 0, stream>>>(
            h1, Wbp, bbp, preds, nullptr, Bc, 0);

        // stage 2
        gather_nb<<<dim3(25 * Bc / 256, 1), 256, 0, stream>>>(preds, a4, A2, Bc, bshift);
        gemm_bt<1,128><<<dim3(Bc / 128, 5, 25), 256, 0, stream>>>(A2, Wat, h2, nullptr, bap,
            352, 640, 1, 1, 1, 352, 352, 640,
            (long long)Bc * 352, 640LL * 352, (long long)Bc * 640, 640, Bc, bshift);
        logits_mfma<2><<<dim3(Bc / 128, 25), 256, 0, stream>>>(
            h2, Wbp, bbp, nullptr, dout, Bc, c * Bc);
    }

    mean_k<<<dim3(320), 256, 0, stream>>>(dout);
}

// Round 6
// 1676.143 us; speedup vs baseline: 1.4500x; 1.0247x over previous
//
#include <hip/hip_runtime.h>

typedef unsigned short u16;
typedef unsigned int u32;

typedef __attribute__((ext_vector_type(8))) __bf16 bf16x8;
typedef __attribute__((ext_vector_type(4))) float f32x4;

__device__ __forceinline__ float bf2f(u16 u) {
    u32 t = ((u32)u) << 16;
    float f;
    __builtin_memcpy(&f, &t, 4);
    return f;
}
__device__ __forceinline__ u16 f2bf(float f) {
    u32 u;
    __builtin_memcpy(&u, &f, 4);
    u32 r = (u + 0x7fffu + ((u >> 16) & 1u)) >> 16;
    return (u16)r;
}
__device__ __forceinline__ float tanh_fast(float x) {
    float xc = fminf(fmaxf(x, -15.f), 15.f);
    float e = __expf(2.f * xc);
    return (e - 1.f) / (e + 1.f);
}

// Async global->LDS DMA, 16B per lane. LDS dest = wave-uniform base + lane*16.
__device__ __forceinline__ void gld16(const u16* g, u16* l) {
    __builtin_amdgcn_global_load_lds(
        (const __attribute__((address_space(1))) u32*)(uintptr_t)g,
        (__attribute__((address_space(3))) u32*)(u32)(uintptr_t)l,
        16, 0, 0);
}

// LDS bank swizzle (round 5, kept): chunk c (16B) of row r staged into slot
// (c + (r>>1)) & 3; consumer reads chunk qd of row R at (qd + (R>>1)) & 3.
// Verified round 5: SQ_LDS_BANK_CONFLICT 5.5M -> 0.

// ---------------------------------------------------------------------------
// bf16 MFMA GEMM, tile 128 x NT, SINGLE-BARRIER PIPELINED K-LOOP (round 6):
// depth-2 LDS double-buffer; prefetch for step st+1 is issued BEFORE compute
// of step st, so the barrier at st+1 drains a load that had the whole MFMA
// phase in flight. Tap x K iteration space flattened with uniform validity-
// skip (no pipeline flush at tap boundaries; no wasted FLOPs on pad taps).
// A: [spatial][Bc][ldA] (k-contiguous). W: [T][N][ldW]. T==9 -> 3x3 conv via
// shift-GEMM (tile sits at one spatial position -> validity block-uniform).
// EPI 0: relu(acc*epiA[n]+epiB[n]); EPI 1: tanh(acc+epiB[n]).
// ---------------------------------------------------------------------------
template <int EPI, int NT>
__global__ __launch_bounds__(256, 3) void gemm_bt(
    const u16* __restrict__ A, const u16* __restrict__ W, u16* __restrict__ O,
    const float* __restrict__ epiA, const float* __restrict__ epiB,
    int Kin, int N, int T, int Himg, int Wimg,
    int ldA, int ldW, int ldO,
    long long Az, long long Wz, long long Oz, int epiZ,
    int Bc, int bshift)
{
    constexpr int NJ = NT / 32;          // 4 (NT=128) or 2 (NT=64)
    __shared__ __align__(16) u16 lsA[2][128 * 32];
    __shared__ __align__(16) u16 lsW[2][NT * 32];

    const int tid = threadIdx.x;
    const int z = blockIdx.z;
    A += (long long)z * Az;
    W += (long long)z * Wz;
    O += (long long)z * Oz;
    epiB += (long long)z * epiZ;

    const int m0 = blockIdx.x * 128;
    const int n0 = blockIdx.y * NT;
    const int s = m0 >> bshift;          // spatial index (0 for MLP)
    const int b0 = m0 & (Bc - 1);        // batch offset
    const int hh0 = s / Wimg, ww0 = s % Wimg;

    const int wave = tid >> 6;
    const int lane = tid & 63;
    const int mbase = (wave >> 1) * 64;
    const int nbase = (wave & 1) * (NT / 2);
    const int ln = lane & 15, qd = lane >> 4;

    const int srow = lane >> 2;                                // staging row in 16-slab
    const int sc = (((lane & 3) - ((srow >> 1) & 3)) & 3) * 8; // swizzled fetch chunk
    const int csel = ((qd + (ln >> 1)) & 3) * 8;               // swizzled read chunk

    // lane-constant staging offsets (elems)
    const int rowA = wave * 32 + srow;
    const int rowW = (NT == 128) ? (wave * 32 + srow) : (wave * 16 + srow);
    const int offA0 = rowA * ldA + sc;
    const int offA1 = offA0 + 16 * ldA;
    const int offW0 = rowW * ldW + sc;
    const int offW1 = offW0 + 16 * ldW;   // NT==128 only
    u16* const lA0 = &lsA[0][0] + wave * 1024;
    u16* const lW0 = (NT == 128) ? (&lsW[0][0] + wave * 1024) : (&lsW[0][0] + wave * 512);
    constexpr int LPAR_A = 128 * 32;      // parity stride (elems)
    constexpr int LPAR_W = NT * 32;

    // tap helpers (all wave-uniform)
    auto tapvalid = [&](int t) -> bool {
        if (T != 9) return true;
        const int hh = hh0 + t / 3 - 1, ww = ww0 + t % 3 - 1;
        return hh >= 0 && hh < Himg && ww >= 0 && ww < Wimg;
    };
    auto tapA = [&](int t) -> const u16* {
        int sp = s;
        if (T == 9) sp = (hh0 + t / 3 - 1) * Wimg + (ww0 + t % 3 - 1);
        return A + (long long)(sp * Bc + b0) * ldA;
    };

    int t0 = 0;
    while (!tapvalid(t0)) ++t0;
    int nvalid = 0;
    for (int t = 0; t < T; ++t) nvalid += tapvalid(t) ? 1 : 0;
    const int KS = Kin >> 5;
    const int S = nvalid * KS;

    const u16* Ab = tapA(t0);
    const u16* Wb = W + ((long long)t0 * N + n0) * ldW;

    // prologue: prefetch step 0 into parity 0
    gld16(Ab + offA0, lA0);
    gld16(Ab + offA1, lA0 + 512);
    gld16(Wb + offW0, lW0);
    if (NT == 128) gld16(Wb + offW1, lW0 + 512);

    int ntap = t0, nkk = 0;

    f32x4 acc[4][NJ];
#pragma unroll
    for (int i = 0; i < 4; ++i)
#pragma unroll
        for (int j = 0; j < NJ; ++j)
            acc[i][j] = (f32x4){0.f, 0.f, 0.f, 0.f};

    for (int st = 0; st < S; ++st) {
        __syncthreads();   // drains prefetch issued at st-1 (had full MFMA phase in flight)
        if (st + 1 < S) {
            nkk += 32;
            if (nkk == Kin) {
                nkk = 0;
                do { ++ntap; } while (!tapvalid(ntap));
                Ab = tapA(ntap);
                Wb = W + ((long long)ntap * N + n0) * ldW;
            }
            const int pp = (st + 1) & 1;
            gld16(Ab + offA0 + nkk, lA0 + pp * LPAR_A);
            gld16(Ab + offA1 + nkk, lA0 + pp * LPAR_A + 512);
            gld16(Wb + offW0 + nkk, lW0 + pp * LPAR_W);
            if (NT == 128) gld16(Wb + offW1 + nkk, lW0 + pp * LPAR_W + 512);
        }
        const int cp = st & 1;
        bf16x8 af[4], bfr[NJ];
#pragma unroll
        for (int f = 0; f < 4; ++f)
            af[f] = *(const bf16x8*)&lsA[cp][(mbase + f * 16 + ln) * 32 + csel];
#pragma unroll
        for (int f = 0; f < NJ; ++f)
            bfr[f] = *(const bf16x8*)&lsW[cp][(nbase + f * 16 + ln) * 32 + csel];
#pragma unroll
        for (int i = 0; i < 4; ++i)
#pragma unroll
            for (int j = 0; j < NJ; ++j)
                acc[i][j] = __builtin_amdgcn_mfma_f32_16x16x32_bf16(
                    af[i], bfr[j], acc[i][j], 0, 0, 0);
    }

#pragma unroll
    for (int j = 0; j < NJ; ++j) {
        const int n = n0 + nbase + j * 16 + ln;
        const float sh = epiB[n];
        float sc2 = 1.f;
        if (EPI == 0) sc2 = epiA[n];
#pragma unroll
        for (int i = 0; i < 4; ++i) {
            const int mrow = mbase + i * 16 + qd * 4;
#pragma unroll
            for (int rr = 0; rr < 4; ++rr) {
                float v = acc[i][j][rr];
                if (EPI == 0) v = fmaxf(v * sc2 + sh, 0.f);
                else          v = tanh_fast(v + sh);
                O[(long long)(m0 + mrow + rr) * ldO + n] = f2bf(v);
            }
        }
    }
}

// ---------------------------------------------------------------------------
// Logits(600->10, padded 640->16) + softmax via MFMA, same single-barrier
// pipelined K-loop. h[n][Bc][640] bf16 (pad cols 0), Wbp[n][16][640] bf16,
// bbp[n][16] fp32 (pad -1e30). C layout col=ln, row=qd*4+rr -> softmax =
// shfl-xor over the 16-lane group.
// ---------------------------------------------------------------------------
template <int STAGE>
__global__ __launch_bounds__(256) void logits_mfma(
    const u16* __restrict__ h, const u16* __restrict__ Wbp, const float* __restrict__ bbp,
    u16* __restrict__ preds, float* __restrict__ dout, int Bc, int gbase)
{
    __shared__ __align__(16) u16 lsA[2][128 * 32];
    __shared__ __align__(16) u16 lsW[2][16 * 32];

    const int tid = threadIdx.x;
    const int n = blockIdx.y;
    const int m0 = blockIdx.x * 128;
    const u16* A = h + ((long long)n * Bc + m0) * 640;
    const u16* Wn = Wbp + n * 16 * 640;

    const int wave = tid >> 6;
    const int lane = tid & 63;
    const int ln = lane & 15, qd = lane >> 4;
    const int srow = lane >> 2;
    const int sc = (((lane & 3) - ((srow >> 1) & 3)) & 3) * 8;
    const int csel = ((qd + (ln >> 1)) & 3) * 8;

    const int offA0 = (wave * 32 + srow) * 640 + sc;
    const int offA1 = offA0 + 16 * 640;
    const int offW0 = srow * 640 + sc;
    u16* const lA0 = &lsA[0][0] + wave * 1024;

    // prologue prefetch (parity 0, k=0)
    gld16(A + offA0, lA0);
    gld16(A + offA1, lA0 + 512);
    if (wave == 0) gld16(Wn + offW0, &lsW[0][0]);

    f32x4 acc[2];
    acc[0] = (f32x4){0.f, 0.f, 0.f, 0.f};
    acc[1] = (f32x4){0.f, 0.f, 0.f, 0.f};

    for (int st = 0; st < 20; ++st) {
        __syncthreads();
        if (st + 1 < 20) {
            const int kk = (st + 1) * 32;
            const int pp = (st + 1) & 1;
            gld16(A + offA0 + kk, lA0 + pp * 4096);
            gld16(A + offA1 + kk, lA0 + pp * 4096 + 512);
            if (wave == 0) gld16(Wn + offW0 + kk, &lsW[pp][0]);
        }
        const int cp = st & 1;
        const bf16x8 bfr = *(const bf16x8*)&lsW[cp][ln * 32 + csel];
        const bf16x8 a0 = *(const bf16x8*)&lsA[cp][(wave * 32 + ln) * 32 + csel];
        const bf16x8 a1 = *(const bf16x8*)&lsA[cp][(wave * 32 + 16 + ln) * 32 + csel];
        acc[0] = __builtin_amdgcn_mfma_f32_16x16x32_bf16(a0, bfr, acc[0], 0, 0, 0);
        acc[1] = __builtin_amdgcn_mfma_f32_16x16x32_bf16(a1, bfr, acc[1], 0, 0, 0);
    }

    const float bias = bbp[n * 16 + ln];
#pragma unroll
    for (int i = 0; i < 2; ++i) {
#pragma unroll
        for (int rr = 0; rr < 4; ++rr) {
            const float v = acc[i][rr] + bias;
            float mx = v;
#pragma unroll
            for (int mk = 1; mk < 16; mk <<= 1)
                mx = fmaxf(mx, __shfl_xor(mx, mk));
            const float e = __expf(v - mx);
            float ssum = e;
#pragma unroll
            for (int mk = 1; mk < 16; mk <<= 1)
                ssum += __shfl_xor(ssum, mk);
            const float p = e / ssum;
            const int row = m0 + wave * 32 + i * 16 + qd * 4 + rr;
            if (ln < 10) {
                if (STAGE == 1)
                    preds[((long long)n * Bc + row) * 10 + ln] = f2bf(p);
                else
                    dout[81920 + ((long long)n * 8192 + gbase + row) * 10 + ln] = p;
            }
        }
    }
}

// ---------------------------------------------------------------------------
// x chunk [Bc,3,20,20] fp32 -> xt [400][Bc][4] bf16 (ch padded to 4, pad=0)
// ---------------------------------------------------------------------------
__global__ __launch_bounds__(256) void transpose_x(
    const float* __restrict__ x, u16* __restrict__ xt, int Bc, int bshift)
{
    const int t = blockIdx.x * 256 + threadIdx.x;
    if (t >= 400 * Bc) return;
    const int s = t >> bshift;
    const int b = t & (Bc - 1);
    const u32 c0 = f2bf(x[((long long)b * 3 + 0) * 400 + s]);
    const u32 c1 = f2bf(x[((long long)b * 3 + 1) * 400 + s]);
    const u32 c2 = f2bf(x[((long long)b * 3 + 2) * 400 + s]);
    uint2 st;
    st.x = c0 | (c1 << 16);
    st.y = c2;                              // high 16 = 0 pad
    *(uint2*)(xt + ((long long)s * Bc + b) * 4) = st;
}

// ---------------------------------------------------------------------------
// im2col for conv1: xt[400][Bc][4] -> xcol[400][Bc][32] (k = tap*3+ci, pad 0).
// ---------------------------------------------------------------------------
__global__ __launch_bounds__(256) void im2col1(
    const u16* __restrict__ xt, u16* __restrict__ xcol, int Bc, int bshift)
{
    const int t = blockIdx.x * 256 + threadIdx.x;
    if (t >= 400 * Bc) return;
    const int s = t >> bshift;
    const int b = t & (Bc - 1);
    const int hh = s / 20, ww = s % 20;

    u32 p0, q0, p1, q1, p2, q2, p3, q3, p4, q4, p5, q5, p6, q6, p7, q7, p8, q8;
#define LOADTAP(T, P, Q)                                                      \
    {                                                                         \
        const int ih = hh + (T) / 3 - 1, iw = ww + (T) % 3 - 1;               \
        P = 0u; Q = 0u;                                                       \
        if (ih >= 0 && ih < 20 && iw >= 0 && iw < 20) {                       \
            const uint2 v = *(const uint2*)(xt +                              \
                ((long long)(ih * 20 + iw) * Bc + b) * 4);                    \
            P = v.x; Q = v.y;                                                 \
        }                                                                     \
    }
    LOADTAP(0, p0, q0) LOADTAP(1, p1, q1) LOADTAP(2, p2, q2)
    LOADTAP(3, p3, q3) LOADTAP(4, p4, q4) LOADTAP(5, p5, q5)
    LOADTAP(6, p6, q6) LOADTAP(7, p7, q7) LOADTAP(8, p8, q8)
#undef LOADTAP

    u16* o = xcol + (long long)t * 32;
    uint4 w;
    w.x = p0;                w.y = q0 | (p1 << 16);
    w.z = (p1 >> 16) | (q1 << 16);
    w.w = p2;
    *(uint4*)(o + 0) = w;
    w.x = q2 | (p3 << 16);   w.y = (p3 >> 16) | (q3 << 16);
    w.z = p4;                w.w = q4 | (p5 << 16);
    *(uint4*)(o + 8) = w;
    w.x = (p5 >> 16) | (q5 << 16);
    w.y = p6;                w.z = q6 | (p7 << 16);
    w.w = (p7 >> 16) | (q7 << 16);
    *(uint4*)(o + 16) = w;
    w.x = p8;                w.y = q8;   // k=24..26 (+pad)
    w.z = 0u;                w.w = 0u;
    *(uint4*)(o + 24) = w;
}

// ---------------------------------------------------------------------------
// maxpool 3x3 s2 p1, square maps: src[Hi*Hi][Bc][CH] -> dst[Ho*Ho][Bc][CH].
// ---------------------------------------------------------------------------
template <int CH>
__global__ __launch_bounds__(256) void pool_k(
    const u16* __restrict__ src, u16* __restrict__ dst, int Bc, int Hi, int Ho)
{
    constexpr int G = CH / 8;
    const int t = blockIdx.x * 256 + threadIdx.x;
    const int cc = t & (G - 1);
    const int b = t / G;
    if (b >= Bc) return;
    const int so = blockIdx.y;
    const int ho = so / Ho, wo = so % Ho;
    float best[8];
#pragma unroll
    for (int e = 0; e < 8; ++e) best[e] = 0.f;
    for (int ph = 0; ph < 3; ++ph) {
        const int hh = 2 * ho - 1 + ph;
        if (hh < 0 || hh >= Hi) continue;
        for (int pw = 0; pw < 3; ++pw) {
            const int ww = 2 * wo - 1 + pw;
            if (ww < 0 || ww >= Hi) continue;
            const uint4 u = *(const uint4*)(src + ((long long)(hh * Hi + ww) * Bc + b) * CH + cc * 8);
            const u32 uw[4] = {u.x, u.y, u.z, u.w};
#pragma unroll
            for (int e = 0; e < 4; ++e) {
                best[2 * e]     = fmaxf(best[2 * e],     bf2f((u16)(uw[e] & 0xffff)));
                best[2 * e + 1] = fmaxf(best[2 * e + 1], bf2f((u16)(uw[e] >> 16)));
            }
        }
    }
    u32 pk[4];
#pragma unroll
    for (int e = 0; e < 4; ++e)
        pk[e] = (u32)f2bf(best[2 * e]) | (((u32)f2bf(best[2 * e + 1])) << 16);
    uint4 st;
    st.x = pk[0]; st.y = pk[1]; st.z = pk[2]; st.w = pk[3];
    *(uint4*)(dst + ((long long)so * Bc + b) * CH + cc * 8) = st;
}

// ---------------------------------------------------------------------------
// Stage-2 input assembly.
// ---------------------------------------------------------------------------
__device__ __forceinline__ void neighbors5x5(int i, int* nb) {
    const int w = 5, size = 25;
    int cnt = 0;
    if (i - w >= 0) nb[cnt++] = i - w;
    if (i % w != 0) nb[cnt++] = i - 1;
    if ((i + 1) % w != 0) nb[cnt++] = i + 1;
    if (i + w < size) nb[cnt++] = i + w;
    if (i - w - 1 >= 0 && i % w != 0) nb[cnt++] = i - w - 1;
    if (i - w + 1 >= 0 && (i + 1) % w != 0) nb[cnt++] = i - w + 1;
    if (i + w - 1 < size && i % w != 0) nb[cnt++] = i + w - 1;
    if (i + w + 1 < size && (i + 1) % w != 0) nb[cnt++] = i + w + 1;
    for (; cnt < 8; ++cnt) nb[cnt] = -1;
}

__global__ __launch_bounds__(256) void gather_nb(
    const u16* __restrict__ preds, const u16* __restrict__ feats, u16* __restrict__ A2,
    int Bc, int bshift)
{
    const int g = blockIdx.x * 256 + threadIdx.x;  // n*Bc+b
    if (g >= 25 * Bc) return;
    const int n = g >> bshift;
    const int b = g & (Bc - 1);
    int nb[8];
    neighbors5x5(n, nb);
    u16* dst = A2 + (long long)g * 352;
#pragma unroll
    for (int j = 0; j < 8; ++j) {
        u32* d32 = (u32*)(dst + j * 10);
        if (nb[j] >= 0) {
            const u32* s32 = (const u32*)(preds + ((long long)nb[j] * Bc + b) * 10);
#pragma unroll
            for (int q = 0; q < 5; ++q) d32[q] = s32[q];
        } else {
#pragma unroll
            for (int q = 0; q < 5; ++q) d32[q] = 0u;
        }
    }
    const uint4* fs = (const uint4*)(feats + (long long)g * 256);
    uint4* fd = (uint4*)(dst + 80);
#pragma unroll
    for (int q = 0; q < 32; ++q) fd[q] = fs[q];
    uint4 z;
    z.x = 0u; z.y = 0u; z.z = 0u; z.w = 0u;
    *(uint4*)(dst + 336) = z;
    *(uint4*)(dst + 344) = z;
}

__global__ __launch_bounds__(256) void mean_k(float* __restrict__ dout)
{
    const int t = blockIdx.x * 256 + threadIdx.x;
    float s = 0.f;
#pragma unroll
    for (int n = 0; n < 25; ++n) s += dout[81920 + n * 81920 + t];
    dout[t] = s * 0.04f;
}

// ---------------------------------------------------------------------------
// Weight/param prep (once per launch)
// ---------------------------------------------------------------------------
__global__ void prep_bn_all(
    const float* b1, const float* g1, const float* be1, const float* m1, const float* v1,
    const float* b2, const float* g2, const float* be2, const float* m2, const float* v2,
    const float* b3, const float* g3, const float* be3, const float* m3, const float* v3,
    const float* b4, const float* g4, const float* be4, const float* m4, const float* v4,
    float* bnA, float* bnB)
{
    const int t = blockIdx.x * 256 + threadIdx.x;
    if (t >= 704) return;
    const float *bp, *gp, *bep, *mp, *vp;
    int idx;
    if (t < 64)       { bp=b1; gp=g1; bep=be1; mp=m1; vp=v1; idx=t; }
    else if (t < 192) { bp=b2; gp=g2; bep=be2; mp=m2; vp=v2; idx=t-64; }
    else if (t < 448) { bp=b3; gp=g3; bep=be3; mp=m3; vp=v3; idx=t-192; }
    else              { bp=b4; gp=g4; bep=be4; mp=m4; vp=v4; idx=t-448; }
    const float A = gp[idx] * rsqrtf(vp[idx] + 1e-5f);
    bnA[t] = A;
    bnB[t] = (bp[idx] - mp[idx]) * A + bep[idx];
}

// W1 [64][3][3][3] -> W1t [64][32], k = tap*3+ci (tap = kh*3+kw), pad 0
__global__ void prep_w1col(const float* __restrict__ W1, u16* __restrict__ W1t)
{
    const int t = blockIdx.x * 256 + threadIdx.x;
    if (t >= 64 * 32) return;
    const int n = t >> 5, k = t & 31;
    u16 v = 0;
    if (k < 27) {
        const int tap = k / 3, ci = k % 3;
        v = f2bf(W1[n * 27 + ci * 9 + tap]);
    }
    W1t[t] = v;
}

// W [Co][Ci][3][3] fp32 -> Wt [9][Co][Ci] bf16
__global__ void prep_convw(const float* __restrict__ W, u16* __restrict__ Wt, int Co, int Ci)
{
    const int t = blockIdx.x * 256 + threadIdx.x;
    const int tot = 9 * Co * Ci;
    if (t >= tot) return;
    const int sh = t / (Co * Ci);
    const int rem = t % (Co * Ci);
    const int co = rem / Ci, ci = rem % Ci;
    Wt[t] = f2bf(W[(long long)(co * Ci + ci) * 9 + sh]);
}

__global__ void prep_wat(const float* __restrict__ Wa, u16* __restrict__ Wat)
{
    const int t = blockIdx.x * 256 + threadIdx.x;
    if (t >= 25 * 640 * 352) return;
    const int n = t / (640 * 352);
    const int rem = t % (640 * 352);
    const int hcol = rem / 352;
    const int k = rem % 352;
    float v = 0.f;
    if (hcol < 600 && k < 336) v = Wa[((long long)n * 336 + k) * 600 + hcol];
    Wat[t] = f2bf(v);
}

__global__ void prep_ba(const float* __restrict__ ba, float* __restrict__ bap)
{
    const int t = blockIdx.x * 256 + threadIdx.x;
    if (t >= 25 * 640) return;
    const int n = t / 640, hcol = t % 640;
    bap[t] = (hcol < 600) ? ba[n * 600 + hcol] : 0.f;
}

// Wb [25][600][10] fp32 -> Wbp [25][16][640] bf16 (transposed, zero-pad);
// bb [25][10] -> bbp [25][16] fp32 (pad -1e30 so softmax ignores pad cols)
__global__ void prep_wbt(const float* __restrict__ Wb, const float* __restrict__ bb,
                         u16* __restrict__ Wbp, float* __restrict__ bbp)
{
    const int t = blockIdx.x * 256 + threadIdx.x;
    if (t < 25 * 16 * 640) {
        const int n = t / (16 * 640);
        const int rem = t % (16 * 640);
        const int c = rem / 640, k = rem % 640;
        u16 v = 0;
        if (c < 10 && k < 600) v = f2bf(Wb[((long long)n * 600 + k) * 10 + c]);
        Wbp[t] = v;
    }
    if (t < 25 * 16) {
        const int n = t >> 4, c = t & 15;
        bbp[t] = (c < 10) ? bb[n * 10 + c] : -1e30f;
    }
}

// ---------------------------------------------------------------------------
extern "C" void kernel_launch(void* const* d_in, const int* in_sizes, int n_in,
                              void* d_out, int out_size, void* d_ws, size_t ws_size,
                              hipStream_t stream)
{
    (void)in_sizes; (void)n_in; (void)out_size;

    const float* x  = (const float*)d_in[0];
    const float* W1 = (const float*)d_in[1];
    const float* b1 = (const float*)d_in[2];
    const float* g1 = (const float*)d_in[3];
    const float* be1= (const float*)d_in[4];
    const float* m1 = (const float*)d_in[5];
    const float* v1 = (const float*)d_in[6];
    const float* W2 = (const float*)d_in[7];
    const float* b2 = (const float*)d_in[8];
    const float* g2 = (const float*)d_in[9];
    const float* be2= (const float*)d_in[10];
    const float* m2 = (const float*)d_in[11];
    const float* v2 = (const float*)d_in[12];
    const float* W3 = (const float*)d_in[13];
    const float* b3 = (const float*)d_in[14];
    const float* g3 = (const float*)d_in[15];
    const float* be3= (const float*)d_in[16];
    const float* m3 = (const float*)d_in[17];
    const float* v3 = (const float*)d_in[18];
    const float* W4 = (const float*)d_in[19];
    const float* b4 = (const float*)d_in[20];
    const float* g4 = (const float*)d_in[21];
    const float* be4= (const float*)d_in[22];
    const float* m4 = (const float*)d_in[23];
    const float* v4 = (const float*)d_in[24];
    const float* Wa = (const float*)d_in[25];
    const float* ba = (const float*)d_in[26];
    const float* Wb = (const float*)d_in[27];
    const float* bb = (const float*)d_in[28];
    float* dout = (float*)d_out;

    // ---- choose Bc: overlay peak = 80000 bytes per batch element ----
    auto al = [](long long v) { return (v + 255LL) & ~255LL; };
    const long long fixedB = al(4096) + al(147456) + al(589824) + al(1179648) +
                             al(11264000) + al(64000) + al(2816) + al(2816) +
                             al(512000) + al(1600);
    int Bc = 256;
    for (int cand = 2048; cand >= 256; cand >>= 1) {
        long long need = fixedB + al(80000LL * cand);
        if (need <= (long long)ws_size) { Bc = cand; break; }
    }
    const int bshift = __builtin_ctz((unsigned)Bc);
    const int C = 8192 / Bc;

    // ---- workspace: fixed region + one overlaid chunk region ----
    char* wsp = (char*)d_ws;
    long long off = 0;
    auto alloc = [&](long long bytes) { long long o = off; off += al(bytes); return o; };
    u16* W1t  = (u16*)(wsp + alloc(4096));
    u16* Wt2  = (u16*)(wsp + alloc(147456));
    u16* Wt3  = (u16*)(wsp + alloc(589824));
    u16* Wt4  = (u16*)(wsp + alloc(1179648));
    u16* Wat  = (u16*)(wsp + alloc(11264000));
    float* bap = (float*)(wsp + alloc(64000));
    float* bnA = (float*)(wsp + alloc(2816));
    float* bnB = (float*)(wsp + alloc(2816));
    u16* Wbp  = (u16*)(wsp + alloc(512000));
    float* bbp = (float*)(wsp + alloc(1600));
    char* ch = wsp + alloc(80000LL * Bc);
    // overlay (bytes-per-elem offsets; lifetimes disjoint where ranges overlap):
    u16* xt   = (u16*)(ch + 0LL     * Bc);   // [0,3200)       t1-t1.5
    u16* xcol = (u16*)(ch + 3200LL  * Bc);   // [3200,28800)   t1.5-t2
    u16* a1   = (u16*)(ch + 28800LL * Bc);   // [28800,80000)  t2-t2.5
    u16* p1   = (u16*)(ch + 0LL     * Bc);   // [0,12800)      t2.5-t3
    u16* a2   = (u16*)(ch + 12800LL * Bc);   // [12800,38400)  t3-t3.5
    u16* p2   = (u16*)(ch + 38400LL * Bc);   // [38400,44800)  t3.5-t4
    u16* a3   = (u16*)(ch + 0LL     * Bc);   // [0,12800)      t4-t5
    u16* a4   = (u16*)(ch + 12800LL * Bc);   // [12800,25600)  t5-t8
    u16* h1   = (u16*)(ch + 25600LL * Bc);   // [25600,57600)  t6-t7
    u16* preds= (u16*)(ch + 57600LL * Bc);   // [57600,58100)  t7-t8
    u16* A2   = (u16*)(ch + 25600LL * Bc);   // [25600,43200)  t8-t9
    u16* h2   = (u16*)(ch + 43200LL * Bc);   // [43200,75200)  t9-t10

    // ---- prep (once) ----
    prep_bn_all<<<dim3(3), 256, 0, stream>>>(b1,g1,be1,m1,v1, b2,g2,be2,m2,v2,
                                             b3,g3,be3,m3,v3, b4,g4,be4,m4,v4, bnA, bnB);
    prep_w1col<<<dim3(8), 256, 0, stream>>>(W1, W1t);
    prep_convw<<<dim3(288),  256, 0, stream>>>(W2, Wt2, 128, 64);
    prep_convw<<<dim3(1152), 256, 0, stream>>>(W3, Wt3, 256, 128);
    prep_convw<<<dim3(2304), 256, 0, stream>>>(W4, Wt4, 256, 256);
    prep_wat<<<dim3(22000), 256, 0, stream>>>(Wa, Wat);
    prep_ba<<<dim3(63), 256, 0, stream>>>(ba, bap);
    prep_wbt<<<dim3(1000), 256, 0, stream>>>(Wb, bb, Wbp, bbp);

    // ---- batch chunks ----
    for (int c = 0; c < C; ++c) {
        const float* xc = x + (long long)c * Bc * 1200;

        transpose_x<<<dim3(400 * Bc / 256), 256, 0, stream>>>(xc, xt, Bc, bshift);
        im2col1<<<dim3(400 * Bc / 256), 256, 0, stream>>>(xt, xcol, Bc, bshift);
        // conv1: flat M = 400*Bc, N=64, K=32 (one k-step), relu+bn epilogue
        gemm_bt<0,64><<<dim3(400 * Bc / 128, 1), 256, 0, stream>>>(xcol, W1t, a1, bnA, bnB,
            32, 64, 1, 1, 1, 32, 32, 64, 0LL, 0LL, 0LL, 0, Bc, bshift);
        pool_k<64><<<dim3(Bc * 8 / 256, 100), 256, 0, stream>>>(a1, p1, Bc, 20, 10);

        gemm_bt<0,128><<<dim3(100 * Bc / 128, 1), 256, 0, stream>>>(p1, Wt2, a2, bnA + 64, bnB + 64,
            64, 128, 9, 10, 10, 64, 64, 128, 0LL, 0LL, 0LL, 0, Bc, bshift);
        pool_k<128><<<dim3(Bc * 16 / 256, 25), 256, 0, stream>>>(a2, p2, Bc, 10, 5);

        gemm_bt<0,128><<<dim3(25 * Bc / 128, 2), 256, 0, stream>>>(p2, Wt3, a3, bnA + 192, bnB + 192,
            128, 256, 9, 5, 5, 128, 128, 256, 0LL, 0LL, 0LL, 0, Bc, bshift);
        gemm_bt<0,128><<<dim3(25 * Bc / 128, 2), 256, 0, stream>>>(a3, Wt4, a4, bnA + 448, bnB + 448,
            256, 256, 9, 5, 5, 256, 256, 256, 0LL, 0LL, 0LL, 0, Bc, bshift);

        // stage 1 MLP: zeros||feats -> only k-rows [80:336) of Wa matter
        gemm_bt<1,128><<<dim3(Bc / 128, 5, 25), 256, 0, stream>>>(a4, Wat + 80, h1, nullptr, bap,
            256, 640, 1, 1, 1, 256, 352, 640,
            (long long)Bc * 256, 640LL * 352, (long long)Bc * 640, 640, Bc, bshift);
        logits_mfma<1><<<dim3(Bc / 128, 25), 256, 0, stream>>>(
            h1, Wbp, bbp, preds, nullptr, Bc, 0);

        // stage 2
        gather_nb<<<dim3(25 * Bc / 256, 1), 256, 0, stream>>>(preds, a4, A2, Bc, bshift);
        gemm_bt<1,128><<<dim3(Bc / 128, 5, 25), 256, 0, stream>>>(A2, Wat, h2, nullptr, bap,
            352, 640, 1, 1, 1, 352, 352, 640,
            (long long)Bc * 352, 640LL * 352, (long long)Bc * 640, 640, Bc, bshift);
        logits_mfma<2><<<dim3(Bc / 128, 25), 256, 0, stream>>>(
            h2, Wbp, bbp, nullptr, dout, Bc, c * Bc);
    }

    mean_k<<<dim3(320), 256, 0, stream>>>(dout);
}